// Round 5
// baseline (3374.713 us; speedup 1.0000x reference)
//
#include <hip/hip_runtime.h>
#include <hip/hip_bf16.h>

#define Bq 256
#define Nn 256
#define Dd 256
#define Uu 256

using bf16 = __hip_bfloat16;

typedef __attribute__((ext_vector_type(8))) short s16x8;
typedef __attribute__((ext_vector_type(4))) float f32x4;

__device__ __forceinline__ float bu2f(unsigned short u) {
  return __uint_as_float(((unsigned)u) << 16);
}
__device__ __forceinline__ unsigned short f2bu(float f) {
  union { bf16 h; unsigned short u; } c; c.h = __float2bfloat16(f); return c.u;
}
__device__ __forceinline__ float sigf(float x) { return 1.0f / (1.0f + __expf(-x)); }
__device__ __forceinline__ float tanh_(float x) { return 2.0f / (1.0f + __expf(-2.0f * x)) - 1.0f; }
__device__ __forceinline__ s16x8 asv(uint4 x) {
  union { uint4 u; s16x8 v; } c; c.u = x; return c.v;
}
#define MFMA16(a, b, c) __builtin_amdgcn_mfma_f32_16x16x32_bf16(a, b, c, 0, 0, 0)

// ---- weight prep: build MFMA B-fragments (bf16) for wiou and wf ----
__global__ __launch_bounds__(256) void prep_weights(
    const float* __restrict__ hiou, const float* __restrict__ hf,
    bf16* __restrict__ wiouB, bf16* __restrict__ wfB) {
  int idx = blockIdx.x * 256 + threadIdx.x;  // 262144 total
  int e = idx & 7, l = (idx >> 3) & 63, kt = (idx >> 9) & 7;
  int k = kt * 32 + (l >> 4) * 8 + e;
  if (idx < 196608) {
    int nt = (idx >> 12) & 15, g = idx >> 16;
    wiouB[idx] = __float2bfloat16(hiou[k * 768 + g * 256 + nt * 16 + (l & 15)]);
  } else {
    int t = idx - 196608;
    int nt = (t >> 12) & 15;
    wfB[t] = __float2bfloat16(hf[k * 256 + nt * 16 + (l & 15)]);
  }
}

// ---- node-info table: nd[blk][t][m] = tgt | par<<8 | om<<16 | pm<<17 ----
__global__ __launch_bounds__(256) void prep_nd(
    const int* __restrict__ parents, const int* __restrict__ post,
    unsigned* __restrict__ ndg) {
  int idx = blockIdx.x * 256 + threadIdx.x;  // 65536
  int b = idx >> 8, t = idx & 255;
  int po = post[b * 256 + t];
  int om = po >= 0;
  int tgt = om ? po : 0;
  int praw = parents[b * 256 + tgt];
  int pm = (praw >= 0) && om;
  int par = praw >= 0 ? praw : 0;
  unsigned word = (unsigned)(tgt & 255) | ((unsigned)(par & 255) << 8) |
                  ((unsigned)om << 16) | ((unsigned)pm << 17);
  ndg[(b >> 4) * 4096 + t * 16 + (b & 15)] = word;
}

// ---- phase 1: fiou_xb = inputs @ x_fiou + bias (unchanged this round) ----
__global__ __launch_bounds__(256) void xproj(
    const float* __restrict__ x, const float* __restrict__ w,
    const float* __restrict__ bias, bf16* __restrict__ out) {
  __shared__ float xs[Dd][16];
  const int tid = threadIdx.x;
  const int row0 = blockIdx.x * 16;
  for (int i = 0; i < 16; ++i) {
    int idx = i * 256 + tid;
    int r = idx >> 8, k = idx & 255;
    xs[k][r] = x[(size_t)(row0 + r) * Dd + k];
  }
  __syncthreads();
  const int c0 = tid * 4;
  float4 bv = *(const float4*)(bias + c0);
  float acc[16][4];
#pragma unroll
  for (int r = 0; r < 16; ++r) {
    acc[r][0] = bv.x; acc[r][1] = bv.y; acc[r][2] = bv.z; acc[r][3] = bv.w;
  }
  for (int k = 0; k < Dd; ++k) {
    float4 wv = *(const float4*)(w + (size_t)k * 1024 + c0);
    const float4* xr = (const float4*)xs[k];
    float4 x0 = xr[0], x1 = xr[1], x2 = xr[2], x3 = xr[3];
    float xv[16] = {x0.x, x0.y, x0.z, x0.w, x1.x, x1.y, x1.z, x1.w,
                    x2.x, x2.y, x2.z, x2.w, x3.x, x3.y, x3.z, x3.w};
#pragma unroll
    for (int r = 0; r < 16; ++r) {
      acc[r][0] += xv[r] * wv.x;
      acc[r][1] += xv[r] * wv.y;
      acc[r][2] += xv[r] * wv.z;
      acc[r][3] += xv[r] * wv.w;
    }
  }
#pragma unroll
  for (int r = 0; r < 16; ++r) {
    union { ushort4 u4; bf16 b[4]; } pk;
    pk.b[0] = __float2bfloat16(acc[r][0]);
    pk.b[1] = __float2bfloat16(acc[r][1]);
    pk.b[2] = __float2bfloat16(acc[r][2]);
    pk.b[3] = __float2bfloat16(acc[r][3]);
    *(ushort4*)(&out[(size_t)(row0 + r) * 1024 + c0]) = pk.u4;
  }
}

// ---- phase 2: MFMA scan ----
// 16 blocks x 512 threads (8 waves). Block owns 16 batches (M=16).
// Wave w owns output cols j in [32w, 32w+32) for gates i,o,u and f.
//
// FAST PATH (per-block, when its 16 batches are exact post-order chains:
// tgt_t = t, par_t = t+1): the recurrent state is just the previous step's
// out-row (kept in LDS ping-pong -- it IS the f-MFMA A operand) and the
// previous step's gated value (register carry, same (m,j) thread owns it
// across steps). No X/gcs global RMW in the loop, ONE barrier per step,
// hs is a fire-and-forget store issued after the barrier.
// SLOW PATH: the previous harness-verified general scan, unchanged.
#define LDH 264
#define SCAN_LDS (131072 + 2 * 16 * LDH * 2)
extern __shared__ char smem[];

__global__ __launch_bounds__(512, 2) void scan3(
    const unsigned short* __restrict__ fiou, const unsigned short* __restrict__ wiouB,
    const unsigned short* __restrict__ wfB, const unsigned* __restrict__ ndg,
    float* __restrict__ X, float* __restrict__ gcs) {
  unsigned short* wf_l  = (unsigned short*)smem;            // 65536 elems
  unsigned short* h_lds = (unsigned short*)(smem + 131072); // 16 x LDH
  unsigned short* o_lds = h_lds + 16 * LDH;                 // 16 x LDH
  __shared__ int okf;

  const int tid = threadIdx.x;
  const int w = tid >> 6, l = tid & 63;
  const int lm = l & 15, lq = l >> 4;
  const int blk = blockIdx.x;
  const int jj = 32 * w + lm;

  if (tid == 0) okf = 1;
  // stage wf B-fragments into LDS (resident across all steps)
  {
    const uint4* s = (const uint4*)wfB;
    uint4* d = (uint4*)wf_l;
    for (int i = tid; i < 8192; i += 512) d[i] = s[i];
  }
  const unsigned* ndb = ndg + blk * 4096;
  const uint4* ndb4 = (const uint4*)ndb;
  uint4 cur4 = ndb4[lq];
  unsigned cur_g = ndb[tid >> 5];
  const uint4* wp = (const uint4*)wiouB;
  __syncthreads();  // okf init visible

  // chain check: ndb[t*16+m] must equal t | (t+1)<<8 | om|pm pattern
  {
    int bad = 0;
#pragma unroll
    for (int k2 = 0; k2 < 8; ++k2) {
      int i = tid + 512 * k2;
      int tt = i >> 4;
      unsigned exp_ = (tt < 255)
          ? ((unsigned)tt | ((unsigned)(tt + 1) << 8) | 0x30000u)
          : (255u | 0x10000u);
      if (ndb[i] != exp_) bad = 1;
    }
    if (bad) atomicAnd(&okf, 0);
  }
  __syncthreads();  // okf final + wf_l staged
  const bool fast = (okf != 0);

  if (fast) {
    // ---------------- FAST PATH ----------------
    // zero the initial h buffer (csh of first targets = 0)
    for (int i = tid; i < 16 * LDH; i += 512) h_lds[i] = 0;
    float gc_[2][4] = {{0.f, 0.f, 0.f, 0.f}, {0.f, 0.f, 0.f, 0.f}};
    __syncthreads();

    unsigned short* obA = h_lds;  // holds out_{t-1} == h_t
    unsigned short* obW = o_lds;  // receives out_t

    for (int t = 0; t < Nn; ++t) {
      unsigned ndr[4] = {cur4.x, cur4.y, cur4.z, cur4.w};

      // fiou gate-row loads (consumed after iou MFMA -> latency hidden)
      unsigned short rxi[2][4], rxo[2][4], rxu[2][4], rxf[2][4];
#pragma unroll
      for (int r = 0; r < 4; ++r) {
        int tgt = ndr[r] & 255, par = (ndr[r] >> 8) & 255;
        int nb = (blk * 16 + 4 * lq + r) << 8;
        const unsigned short* fT = fiou + ((size_t)(nb + tgt) << 10);
        const unsigned short* fP = fiou + ((size_t)(nb + par) << 10);
#pragma unroll
        for (int ts = 0; ts < 2; ++ts) {
          int j = jj + ts * 16;
          rxi[ts][r] = fT[256 + j];
          rxo[ts][r] = fT[512 + j];
          rxu[ts][r] = fT[768 + j];
          rxf[ts][r] = fP[j];
        }
      }

      // wiou stream prologue: 4-deep ring (refill distance >> L2 latency)
      uint4 st[4][3][2];
#pragma unroll
      for (int kt = 0; kt < 4; ++kt)
#pragma unroll
        for (int g = 0; g < 3; ++g)
#pragma unroll
          for (int ts = 0; ts < 2; ++ts)
            st[kt][g][ts] = wp[((g * 16 + (2 * w + ts)) * 8 + kt) * 64 + l];

      // prefetch next step's node info
      const int tn = t < Nn - 1 ? t + 1 : t;
      uint4 nxt4 = ndb4[tn * 4 + lq];

      // iou MFMA: h(16x256) @ wiou(256x768), A from obA (no barrier needed:
      // obA was complete at the previous step's barrier)
      f32x4 z4 = {0.f, 0.f, 0.f, 0.f};
      f32x4 aI[2] = {z4, z4}, aO[2] = {z4, z4}, aU[2] = {z4, z4};
#pragma unroll
      for (int kt = 0; kt < 8; ++kt) {
        uint4 av = *(const uint4*)&obA[lm * LDH + kt * 32 + lq * 8];
        s16x8 a = asv(av);
#pragma unroll
        for (int ts = 0; ts < 2; ++ts) {
          aI[ts] = MFMA16(a, asv(st[kt & 3][0][ts]), aI[ts]);
          aO[ts] = MFMA16(a, asv(st[kt & 3][1][ts]), aO[ts]);
          aU[ts] = MFMA16(a, asv(st[kt & 3][2][ts]), aU[ts]);
        }
        if (kt < 4) {
#pragma unroll
          for (int g = 0; g < 3; ++g)
#pragma unroll
            for (int ts = 0; ts < 2; ++ts)
              st[kt][g][ts] = wp[((g * 16 + (2 * w + ts)) * 8 + (kt + 4)) * 64 + l];
        }
      }

      // gating; gcs[tgt] is the register carry gc_ (single-child chain)
      float mem_[2][4], out_[2][4];
#pragma unroll
      for (int ts = 0; ts < 2; ++ts)
#pragma unroll
        for (int r = 0; r < 4; ++r) {
          float I = aI[ts][r] + bu2f(rxi[ts][r]);
          float O = aO[ts][r] + bu2f(rxo[ts][r]);
          float Uv = aU[ts][r] + bu2f(rxu[ts][r]);
          float memv = sigf(I) * tanh_(Uv) + gc_[ts][r];
          float outv = sigf(O) * tanh_(memv);
          mem_[ts][r] = memv;
          out_[ts][r] = outv;
          obW[(4 * lq + r) * LDH + jj + ts * 16] = f2bu(outv);
        }
      __syncthreads();  // obW (= out_t) ready; doubles as h_{t+1}

      // hs store AFTER the barrier: its vmcnt drain hides under next step
#pragma unroll
      for (int ts = 0; ts < 2; ++ts)
#pragma unroll
        for (int r = 0; r < 4; ++r) {
          int tgt = ndr[r] & 255;
          int nb = (blk * 16 + 4 * lq + r) << 8;
          X[((size_t)(nb + tgt) << 8) + jj + ts * 16] = out_[ts][r];
        }

      // f MFMA: out(16x256) @ wf(256x256), wf frags LDS-resident
      f32x4 aF[2] = {z4, z4};
#pragma unroll
      for (int kt = 0; kt < 8; ++kt) {
        uint4 av = *(const uint4*)&obW[lm * LDH + kt * 32 + lq * 8];
        s16x8 a = asv(av);
#pragma unroll
        for (int ts = 0; ts < 2; ++ts) {
          uint4 bv = *(const uint4*)&wf_l[(((2 * w + ts) * 8 + kt) * 64 + l) * 8];
          aF[ts] = MFMA16(a, asv(bv), aF[ts]);
        }
      }

      // carry update: gcs[par=t+1] = gated_t (register, same thread owns it)
#pragma unroll
      for (int ts = 0; ts < 2; ++ts)
#pragma unroll
        for (int r = 0; r < 4; ++r) {
          float AF = aF[ts][r] + bu2f(rxf[ts][r]);
          gc_[ts][r] = sigf(AF) * mem_[ts][r];
        }

      // ping-pong: out_t becomes h_{t+1}
      unsigned short* tmp = obA; obA = obW; obW = tmp;
      cur4 = nxt4;
    }
  } else {
    // ---------------- SLOW PATH (general trees; unchanged) ----------------
    for (int t = 0; t < Nn; ++t) {
      const int r16 = tid >> 5, c8 = (tid & 31) * 8;
      int nrh = ((blk * 16 + r16) << 8) + (int)(cur_g & 255);
      const float* xr = X + ((size_t)nrh << 8) + c8;
      float4 a0 = ((const float4*)xr)[0];
      float4 a1 = ((const float4*)xr)[1];

      unsigned ndr[4] = {cur4.x, cur4.y, cur4.z, cur4.w};

      unsigned short rxi[2][4], rxo[2][4], rxu[2][4], rxf[2][4];
      float rgc[2][4], xold[2][4], gold[2][4];
#pragma unroll
      for (int r = 0; r < 4; ++r) {
        int tgt = ndr[r] & 255, par = (ndr[r] >> 8) & 255;
        int nb = (blk * 16 + 4 * lq + r) << 8;
        int nrT = nb + tgt, nrP = nb + par;
        const unsigned short* fT = fiou + ((size_t)nrT << 10);
        const unsigned short* fP = fiou + ((size_t)nrP << 10);
#pragma unroll
        for (int ts = 0; ts < 2; ++ts) {
          int j = jj + ts * 16;
          rxi[ts][r] = fT[256 + j];
          rxo[ts][r] = fT[512 + j];
          rxu[ts][r] = fT[768 + j];
          rxf[ts][r] = fP[j];
          rgc[ts][r]  = gcs[((size_t)nrT << 8) + j];
          xold[ts][r] = X[((size_t)nrP << 8) + j];
          gold[ts][r] = gcs[((size_t)nrP << 8) + j];
        }
      }

      uint4 st[2][3][2];
#pragma unroll
      for (int g = 0; g < 3; ++g)
#pragma unroll
        for (int ts = 0; ts < 2; ++ts) {
          st[0][g][ts] = wp[((g * 16 + (2 * w + ts)) * 8 + 0) * 64 + l];
          st[1][g][ts] = wp[((g * 16 + (2 * w + ts)) * 8 + 1) * 64 + l];
        }

      {
        ushort4 p0, p1;
        p0.x = f2bu(a0.x); p0.y = f2bu(a0.y); p0.z = f2bu(a0.z); p0.w = f2bu(a0.w);
        p1.x = f2bu(a1.x); p1.y = f2bu(a1.y); p1.z = f2bu(a1.z); p1.w = f2bu(a1.w);
        *(ushort4*)&h_lds[r16 * LDH + c8] = p0;
        *(ushort4*)&h_lds[r16 * LDH + c8 + 4] = p1;
      }
      __syncthreads();  // B1

      const int tn = t < Nn - 1 ? t + 1 : t;
      uint4 nxt4 = ndb4[tn * 4 + lq];
      unsigned nxt_g = ndb[tn * 16 + (tid >> 5)];

      f32x4 z4 = {0.f, 0.f, 0.f, 0.f};
      f32x4 aI[2] = {z4, z4}, aO[2] = {z4, z4}, aU[2] = {z4, z4};
#pragma unroll
      for (int kt = 0; kt < 8; ++kt) {
        uint4 av = *(const uint4*)&h_lds[lm * LDH + kt * 32 + lq * 8];
        s16x8 a = asv(av);
#pragma unroll
        for (int ts = 0; ts < 2; ++ts) {
          aI[ts] = MFMA16(a, asv(st[kt & 1][0][ts]), aI[ts]);
          aO[ts] = MFMA16(a, asv(st[kt & 1][1][ts]), aO[ts]);
          aU[ts] = MFMA16(a, asv(st[kt & 1][2][ts]), aU[ts]);
        }
        if (kt < 6) {
#pragma unroll
          for (int g = 0; g < 3; ++g)
#pragma unroll
            for (int ts = 0; ts < 2; ++ts)
              st[kt & 1][g][ts] = wp[((g * 16 + (2 * w + ts)) * 8 + (kt + 2)) * 64 + l];
        }
      }

      float mem_[2][4], out_[2][4];
#pragma unroll
      for (int ts = 0; ts < 2; ++ts)
#pragma unroll
        for (int r = 0; r < 4; ++r) {
          float I = aI[ts][r] + bu2f(rxi[ts][r]);
          float O = aO[ts][r] + bu2f(rxo[ts][r]);
          float Uv = aU[ts][r] + bu2f(rxu[ts][r]);
          float memv = sigf(I) * tanh_(Uv) + rgc[ts][r];
          float outv = sigf(O) * tanh_(memv);
          mem_[ts][r] = memv;
          out_[ts][r] = outv;
          o_lds[(4 * lq + r) * LDH + jj + ts * 16] = f2bu(outv);
        }
      __syncthreads();  // B2

      f32x4 aF[2] = {z4, z4};
#pragma unroll
      for (int kt = 0; kt < 8; ++kt) {
        uint4 av = *(const uint4*)&o_lds[lm * LDH + kt * 32 + lq * 8];
        s16x8 a = asv(av);
#pragma unroll
        for (int ts = 0; ts < 2; ++ts) {
          uint4 bv = *(const uint4*)&wf_l[(((2 * w + ts) * 8 + kt) * 64 + l) * 8];
          aF[ts] = MFMA16(a, asv(bv), aF[ts]);
        }
      }

#pragma unroll
      for (int ts = 0; ts < 2; ++ts)
#pragma unroll
        for (int r = 0; r < 4; ++r) {
          unsigned nd_ = ndr[r];
          int tgt = nd_ & 255, par = (nd_ >> 8) & 255;
          int nb = (blk * 16 + 4 * lq + r) << 8;
          int j = jj + ts * 16;
          float AF = aF[ts][r] + bu2f(rxf[ts][r]);
          float gated = sigf(AF) * mem_[ts][r];
          if (nd_ & 0x10000u) X[((size_t)(nb + tgt) << 8) + j] = out_[ts][r];
          if (nd_ & 0x20000u) {
            X[((size_t)(nb + par) << 8) + j] = xold[ts][r] + out_[ts][r];
            gcs[((size_t)(nb + par) << 8) + j] = gold[ts][r] + gated;
          }
        }
      __syncthreads();  // B3
      cur4 = nxt4;
      cur_g = nxt_g;
    }
  }
}

extern "C" void kernel_launch(void* const* d_in, const int* in_sizes, int n_in,
                              void* d_out, int out_size, void* d_ws, size_t ws_size,
                              hipStream_t stream) {
  const float* inputs = (const float*)d_in[0];
  const int* parents  = (const int*)d_in[1];
  const int* post     = (const int*)d_in[2];
  const float* xw     = (const float*)d_in[3];
  const float* hf     = (const float*)d_in[4];
  const float* hiou   = (const float*)d_in[5];
  const float* bias   = (const float*)d_in[6];
  float* X = (float*)d_out;  // csh-then-hs buffer (fast path: hs only)

  // ws layout (~192.8 MiB):
  //   [0, 128 MiB)   fiou_xb bf16  (B*N*4U)
  //   +134217728     gcs fp32      (B*N*U)   64 MiB
  //   +201326592     wiouB bf16    384 KiB
  //   +201719808     wfB bf16      128 KiB
  //   +201850880     ndg u32       256 KiB
  char* ws = (char*)d_ws;
  bf16* fiou     = (bf16*)ws;
  float* gcs     = (float*)(ws + (size_t)134217728);
  bf16* wiouB    = (bf16*)(ws + (size_t)201326592);
  bf16* wfB      = (bf16*)(ws + (size_t)201719808);
  unsigned* ndg  = (unsigned*)(ws + (size_t)201850880);

  hipMemsetAsync(X, 0, (size_t)Bq * Nn * Uu * sizeof(float), stream);
  hipMemsetAsync(gcs, 0, (size_t)Bq * Nn * Uu * sizeof(float), stream);

  hipFuncSetAttribute(reinterpret_cast<const void*>(scan3),
                      hipFuncAttributeMaxDynamicSharedMemorySize, SCAN_LDS);

  prep_weights<<<1024, 256, 0, stream>>>(hiou, hf, wiouB, wfB);
  prep_nd<<<256, 256, 0, stream>>>(parents, post, ndg);
  xproj<<<(Bq * Nn) / 16, 256, 0, stream>>>(inputs, xw, bias, (bf16*)fiou);
  scan3<<<16, 512, SCAN_LDS, stream>>>((const unsigned short*)fiou,
                                       (const unsigned short*)wiouB,
                                       (const unsigned short*)wfB,
                                       ndg, X, gcs);
}

// Round 7
// 2890.025 us; speedup vs baseline: 1.1677x; 1.1677x over previous
//
#include <hip/hip_runtime.h>
#include <hip/hip_bf16.h>

#define Bq 256
#define Nn 256
#define Dd 256
#define Uu 256

using bf16 = __hip_bfloat16;

typedef __attribute__((ext_vector_type(8))) short s16x8;
typedef __attribute__((ext_vector_type(4))) float f32x4;

__device__ __forceinline__ float bu2f(unsigned short u) {
  return __uint_as_float(((unsigned)u) << 16);
}
__device__ __forceinline__ unsigned short f2bu(float f) {
  union { bf16 h; unsigned short u; } c; c.h = __float2bfloat16(f); return c.u;
}
__device__ __forceinline__ float sigf(float x) { return 1.0f / (1.0f + __expf(-x)); }
__device__ __forceinline__ float tanh_(float x) { return 2.0f / (1.0f + __expf(-2.0f * x)) - 1.0f; }
__device__ __forceinline__ s16x8 asv(uint4 x) {
  union { uint4 u; s16x8 v; } c; c.u = x; return c.v;
}
#define MFMA16(a, b, c) __builtin_amdgcn_mfma_f32_16x16x32_bf16(a, b, c, 0, 0, 0)

// ---- weight prep: build MFMA B-fragments (bf16) for wiou and wf ----
// wiouB layout: gate-major (g=0:i, g=1:o, g=2:u), 65536 elems (128 KB) per gate.
__global__ __launch_bounds__(256) void prep_weights(
    const float* __restrict__ hiou, const float* __restrict__ hf,
    bf16* __restrict__ wiouB, bf16* __restrict__ wfB) {
  int idx = blockIdx.x * 256 + threadIdx.x;  // 262144 total
  int e = idx & 7, l = (idx >> 3) & 63, kt = (idx >> 9) & 7;
  int k = kt * 32 + (l >> 4) * 8 + e;
  if (idx < 196608) {
    int nt = (idx >> 12) & 15, g = idx >> 16;
    wiouB[idx] = __float2bfloat16(hiou[k * 768 + g * 256 + nt * 16 + (l & 15)]);
  } else {
    int t = idx - 196608;
    int nt = (t >> 12) & 15;
    wfB[t] = __float2bfloat16(hf[k * 256 + nt * 16 + (l & 15)]);
  }
}

// ---- node-info table: nd[blk][t][m] = tgt | par<<8 | om<<16 | pm<<17 ----
__global__ __launch_bounds__(256) void prep_nd(
    const int* __restrict__ parents, const int* __restrict__ post,
    unsigned* __restrict__ ndg) {
  int idx = blockIdx.x * 256 + threadIdx.x;  // 65536
  int b = idx >> 8, t = idx & 255;
  int po = post[b * 256 + t];
  int om = po >= 0;
  int tgt = om ? po : 0;
  int praw = parents[b * 256 + tgt];
  int pm = (praw >= 0) && om;
  int par = praw >= 0 ? praw : 0;
  unsigned word = (unsigned)(tgt & 255) | ((unsigned)(par & 255) << 8) |
                  ((unsigned)om << 16) | ((unsigned)pm << 17);
  ndg[(b >> 4) * 4096 + t * 16 + (b & 15)] = word;
}

// ---- phase 1: fiou_xb = inputs @ x_fiou + bias (unchanged this round) ----
__global__ __launch_bounds__(256) void xproj(
    const float* __restrict__ x, const float* __restrict__ w,
    const float* __restrict__ bias, bf16* __restrict__ out) {
  __shared__ float xs[Dd][16];
  const int tid = threadIdx.x;
  const int row0 = blockIdx.x * 16;
  for (int i = 0; i < 16; ++i) {
    int idx = i * 256 + tid;
    int r = idx >> 8, k = idx & 255;
    xs[k][r] = x[(size_t)(row0 + r) * Dd + k];
  }
  __syncthreads();
  const int c0 = tid * 4;
  float4 bv = *(const float4*)(bias + c0);
  float acc[16][4];
#pragma unroll
  for (int r = 0; r < 16; ++r) {
    acc[r][0] = bv.x; acc[r][1] = bv.y; acc[r][2] = bv.z; acc[r][3] = bv.w;
  }
  for (int k = 0; k < Dd; ++k) {
    float4 wv = *(const float4*)(w + (size_t)k * 1024 + c0);
    const float4* xr = (const float4*)xs[k];
    float4 x0 = xr[0], x1 = xr[1], x2 = xr[2], x3 = xr[3];
    float xv[16] = {x0.x, x0.y, x0.z, x0.w, x1.x, x1.y, x1.z, x1.w,
                    x2.x, x2.y, x2.z, x2.w, x3.x, x3.y, x3.z, x3.w};
#pragma unroll
    for (int r = 0; r < 16; ++r) {
      acc[r][0] += xv[r] * wv.x;
      acc[r][1] += xv[r] * wv.y;
      acc[r][2] += xv[r] * wv.z;
      acc[r][3] += xv[r] * wv.w;
    }
  }
#pragma unroll
  for (int r = 0; r < 16; ++r) {
    union { ushort4 u4; bf16 b[4]; } pk;
    pk.b[0] = __float2bfloat16(acc[r][0]);
    pk.b[1] = __float2bfloat16(acc[r][1]);
    pk.b[2] = __float2bfloat16(acc[r][2]);
    pk.b[3] = __float2bfloat16(acc[r][3]);
    *(ushort4*)(&out[(size_t)(row0 + r) * 1024 + c0]) = pk.u4;
  }
}

// ---- phase 2: MFMA scan, RESIDENT weights ----
// 16 blocks x 512 threads (8 waves). Block owns 16 batches (M=16).
// Weight residency (was: wiou 384 KB STREAMED from L2 every step = ~3000
// cy/step of pure L2 BW + in-order-vmcnt poisoning by HBM fiou loads):
//   i-gate (128 KB) -> LDS;  u-gate + wf (64+64 regs/wave) -> registers;
//   o-gate (128 KB/step) -> streamed via 2-slot ring, prologue for t+1
//   issued BEFORE the step's HBM fiou prefetch (vmcnt retires in order).
#define LDH 264
#define SCAN_LDS (131072 + 2 * 16 * LDH * 2)
extern __shared__ char smem[];

__global__ __launch_bounds__(512, 2) void scan3(
    const unsigned short* __restrict__ fiou, const unsigned short* __restrict__ wiouB,
    const unsigned short* __restrict__ wfB, const unsigned* __restrict__ ndg,
    float* __restrict__ X, float* __restrict__ gcs) {
  unsigned short* i_lds = (unsigned short*)smem;            // 65536 elems: i-gate frags
  unsigned short* h_lds = (unsigned short*)(smem + 131072); // 16 x LDH
  unsigned short* o_lds = h_lds + 16 * LDH;                 // 16 x LDH
  __shared__ int okf;

  const int tid = threadIdx.x;
  const int w = tid >> 6, l = tid & 63;
  const int lm = l & 15, lq = l >> 4;
  const int blk = blockIdx.x;
  const int jj = 32 * w + lm;
  const int nt0 = 2 * w;  // wave's first col-tile

  if (tid == 0) okf = 1;
  const uint4* wp  = (const uint4*)wiouB;
  const uint4* wf4 = (const uint4*)wfB;
  // stage i-gate (g=0 = first 8192 uint4 of wiouB) into LDS
  {
    uint4* d = (uint4*)i_lds;
    for (int i = tid; i < 8192; i += 512) d[i] = wp[i];
  }
  const unsigned* ndb = ndg + blk * 4096;
  const uint4* ndb4 = (const uint4*)ndb;
  uint4 cur4 = ndb4[lq];
  unsigned cur_g = ndb[tid >> 5];
  __syncthreads();  // okf init visible

  // chain check: ndb[t*16+m] must equal t | (t+1)<<8 | om|pm pattern
  {
    int bad = 0;
#pragma unroll
    for (int k2 = 0; k2 < 8; ++k2) {
      int i = tid + 512 * k2;
      int tt = i >> 4;
      unsigned exp_ = (tt < 255)
          ? ((unsigned)tt | ((unsigned)(tt + 1) << 8) | 0x30000u)
          : (255u | 0x10000u);
      if (ndb[i] != exp_) bad = 1;
    }
    if (bad) atomicAnd(&okf, 0);
  }
  __syncthreads();  // okf final + i_lds staged
  const bool fast = (okf != 0);

  if (fast) {
    // ---------------- FAST PATH (chain) ----------------
    // u-gate (g=2) and wf fragments -> registers, loaded once
    uint4 wur[2][8], wfr[2][8];
#pragma unroll
    for (int ts = 0; ts < 2; ++ts)
#pragma unroll
      for (int kt = 0; kt < 8; ++kt) {
        wur[ts][kt] = wp[((32 + (nt0 + ts)) * 8 + kt) * 64 + l];
        wfr[ts][kt] = wf4[((nt0 + ts) * 8 + kt) * 64 + l];
      }
    // zero initial h buffer (csh of first targets = 0)
    for (int i = tid; i < 16 * LDH; i += 512) h_lds[i] = 0;
    float gc_[2][4] = {{0.f, 0.f, 0.f, 0.f}, {0.f, 0.f, 0.f, 0.f}};

    // fiou rows for t=0 (tgt=0, par=1)
    unsigned short rxi[2][4], rxo[2][4], rxu[2][4], rxf[2][4];
#pragma unroll
    for (int r = 0; r < 4; ++r) {
      int nb = (blk * 16 + 4 * lq + r) << 8;
      const unsigned short* fT = fiou + ((size_t)(nb + 0) << 10);
      const unsigned short* fP = fiou + ((size_t)(nb + 1) << 10);
#pragma unroll
      for (int ts = 0; ts < 2; ++ts) {
        int j = jj + ts * 16;
        rxi[ts][r] = fT[256 + j];
        rxo[ts][r] = fT[512 + j];
        rxu[ts][r] = fT[768 + j];
        rxf[ts][r] = fP[j];
      }
    }
    // o-gate (g=1) ring prologue: kt = 0,1
    uint4 st[2][2];
#pragma unroll
    for (int s = 0; s < 2; ++s)
#pragma unroll
      for (int ts = 0; ts < 2; ++ts)
        st[s][ts] = wp[((16 + (nt0 + ts)) * 8 + s) * 64 + l];
    __syncthreads();  // h zero visible

    unsigned short* obA = h_lds;  // holds out_{t-1} == h_t
    unsigned short* obW = o_lds;  // receives out_t
    const uint4* il4 = (const uint4*)i_lds;
    const f32x4 z4 = {0.f, 0.f, 0.f, 0.f};

    for (int t = 0; t < Nn; ++t) {
      // iou MFMA: h(16x256) @ [i|o|u]; i from LDS, u from regs, o from ring
      f32x4 aI[2] = {z4, z4}, aO[2] = {z4, z4}, aU[2] = {z4, z4};
#pragma unroll
      for (int kt = 0; kt < 8; ++kt) {
        uint4 av = *(const uint4*)&obA[lm * LDH + kt * 32 + lq * 8];
        s16x8 a = asv(av);
#pragma unroll
        for (int ts = 0; ts < 2; ++ts) {
          aI[ts] = MFMA16(a, asv(il4[((nt0 + ts) * 8 + kt) * 64 + l]), aI[ts]);
          aU[ts] = MFMA16(a, asv(wur[ts][kt]), aU[ts]);
          aO[ts] = MFMA16(a, asv(st[kt & 1][ts]), aO[ts]);
        }
        if (kt < 6) {
#pragma unroll
          for (int ts = 0; ts < 2; ++ts)
            st[kt & 1][ts] = wp[((16 + (nt0 + ts)) * 8 + (kt + 2)) * 64 + l];
        }
      }

      // gating (gcs[tgt] is the register carry gc_); write obW + hs store
      float mem_[2][4], out_[2][4];
#pragma unroll
      for (int ts = 0; ts < 2; ++ts)
#pragma unroll
        for (int r = 0; r < 4; ++r) {
          float I = aI[ts][r] + bu2f(rxi[ts][r]);
          float O = aO[ts][r] + bu2f(rxo[ts][r]);
          float Uv = aU[ts][r] + bu2f(rxu[ts][r]);
          float memv = sigf(I) * tanh_(Uv) + gc_[ts][r];
          float outv = sigf(O) * tanh_(memv);
          mem_[ts][r] = memv;
          out_[ts][r] = outv;
          obW[(4 * lq + r) * LDH + jj + ts * 16] = f2bu(outv);
          int nb = (blk * 16 + 4 * lq + r) << 8;
          X[((size_t)(nb + t) << 8) + jj + ts * 16] = outv;
        }

      // o-ring prologue for t+1: L2 loads issued BEFORE the HBM fiou
      // prefetch below (vmcnt retires in order -- keep L2 ahead of HBM).
      // Addresses are t-independent, so reload unconditionally.
#pragma unroll
      for (int s = 0; s < 2; ++s)
#pragma unroll
        for (int ts = 0; ts < 2; ++ts)
          st[s][ts] = wp[((16 + (nt0 + ts)) * 8 + s) * 64 + l];

      // fiou iou-gate prefetch for t+1 (chain: tgt_{t+1} = t+1)
      {
        int tgtN = (t < Nn - 1) ? t + 1 : t;  // clamped; last iter unused
#pragma unroll
        for (int r = 0; r < 4; ++r) {
          int nb = (blk * 16 + 4 * lq + r) << 8;
          const unsigned short* fT = fiou + ((size_t)(nb + tgtN) << 10);
#pragma unroll
          for (int ts = 0; ts < 2; ++ts) {
            int j = jj + ts * 16;
            rxi[ts][r] = fT[256 + j];
            rxo[ts][r] = fT[512 + j];
            rxu[ts][r] = fT[768 + j];
          }
        }
      }
      __syncthreads();  // obW (= out_t) ready; doubles as h_{t+1}

      // f MFMA: out(16x256) @ wf(256x256), wf frags register-resident
      f32x4 aF[2] = {z4, z4};
#pragma unroll
      for (int kt = 0; kt < 8; ++kt) {
        uint4 av = *(const uint4*)&obW[lm * LDH + kt * 32 + lq * 8];
        s16x8 a = asv(av);
#pragma unroll
        for (int ts = 0; ts < 2; ++ts)
          aF[ts] = MFMA16(a, asv(wfr[ts][kt]), aF[ts]);
      }

      // carry update: gcs[par=t+1] = gated_t (register, same thread owns it)
#pragma unroll
      for (int ts = 0; ts < 2; ++ts)
#pragma unroll
        for (int r = 0; r < 4; ++r) {
          float AF = aF[ts][r] + bu2f(rxf[ts][r]);
          gc_[ts][r] = sigf(AF) * mem_[ts][r];
        }

      // f-gate prefetch for t+1 (par_{t+1} = t+2; table maps last par -> 0)
      {
        int tgtN = (t < Nn - 1) ? t + 1 : t;
        int parN = (tgtN < 255) ? tgtN + 1 : 0;
#pragma unroll
        for (int r = 0; r < 4; ++r) {
          int nb = (blk * 16 + 4 * lq + r) << 8;
          const unsigned short* fP = fiou + ((size_t)(nb + parN) << 10);
#pragma unroll
          for (int ts = 0; ts < 2; ++ts)
            rxf[ts][r] = fP[jj + ts * 16];
        }
      }

      // ping-pong: out_t becomes h_{t+1}
      unsigned short* tmp = obA; obA = obW; obW = tmp;
    }
  } else {
    // ---------------- SLOW PATH (general trees) ----------------
    // Structure identical to the harness-verified general scan; only the
    // f-MFMA B source changed (wf_l LDS is gone -> direct global loads).
    for (int t = 0; t < Nn; ++t) {
      const int r16 = tid >> 5, c8 = (tid & 31) * 8;
      int nrh = ((blk * 16 + r16) << 8) + (int)(cur_g & 255);
      const float* xr = X + ((size_t)nrh << 8) + c8;
      float4 a0 = ((const float4*)xr)[0];
      float4 a1 = ((const float4*)xr)[1];

      unsigned ndr[4] = {cur4.x, cur4.y, cur4.z, cur4.w};

      unsigned short rxi[2][4], rxo[2][4], rxu[2][4], rxf[2][4];
      float rgc[2][4], xold[2][4], gold[2][4];
#pragma unroll
      for (int r = 0; r < 4; ++r) {
        int tgt = ndr[r] & 255, par = (ndr[r] >> 8) & 255;
        int nb = (blk * 16 + 4 * lq + r) << 8;
        int nrT = nb + tgt, nrP = nb + par;
        const unsigned short* fT = fiou + ((size_t)nrT << 10);
        const unsigned short* fP = fiou + ((size_t)nrP << 10);
#pragma unroll
        for (int ts = 0; ts < 2; ++ts) {
          int j = jj + ts * 16;
          rxi[ts][r] = fT[256 + j];
          rxo[ts][r] = fT[512 + j];
          rxu[ts][r] = fT[768 + j];
          rxf[ts][r] = fP[j];
          rgc[ts][r]  = gcs[((size_t)nrT << 8) + j];
          xold[ts][r] = X[((size_t)nrP << 8) + j];
          gold[ts][r] = gcs[((size_t)nrP << 8) + j];
        }
      }

      uint4 st2[2][3][2];
#pragma unroll
      for (int g = 0; g < 3; ++g)
#pragma unroll
        for (int ts = 0; ts < 2; ++ts) {
          st2[0][g][ts] = wp[((g * 16 + (nt0 + ts)) * 8 + 0) * 64 + l];
          st2[1][g][ts] = wp[((g * 16 + (nt0 + ts)) * 8 + 1) * 64 + l];
        }

      {
        ushort4 p0, p1;
        p0.x = f2bu(a0.x); p0.y = f2bu(a0.y); p0.z = f2bu(a0.z); p0.w = f2bu(a0.w);
        p1.x = f2bu(a1.x); p1.y = f2bu(a1.y); p1.z = f2bu(a1.z); p1.w = f2bu(a1.w);
        *(ushort4*)&h_lds[r16 * LDH + c8] = p0;
        *(ushort4*)&h_lds[r16 * LDH + c8 + 4] = p1;
      }
      __syncthreads();  // B1

      const int tn = t < Nn - 1 ? t + 1 : t;
      uint4 nxt4 = ndb4[tn * 4 + lq];
      unsigned nxt_g = ndb[tn * 16 + (tid >> 5)];

      f32x4 z4 = {0.f, 0.f, 0.f, 0.f};
      f32x4 aI[2] = {z4, z4}, aO[2] = {z4, z4}, aU[2] = {z4, z4};
#pragma unroll
      for (int kt = 0; kt < 8; ++kt) {
        uint4 av = *(const uint4*)&h_lds[lm * LDH + kt * 32 + lq * 8];
        s16x8 a = asv(av);
#pragma unroll
        for (int ts = 0; ts < 2; ++ts) {
          aI[ts] = MFMA16(a, asv(st2[kt & 1][0][ts]), aI[ts]);
          aO[ts] = MFMA16(a, asv(st2[kt & 1][1][ts]), aO[ts]);
          aU[ts] = MFMA16(a, asv(st2[kt & 1][2][ts]), aU[ts]);
        }
        if (kt < 6) {
#pragma unroll
          for (int g = 0; g < 3; ++g)
#pragma unroll
            for (int ts = 0; ts < 2; ++ts)
              st2[kt & 1][g][ts] = wp[((g * 16 + (nt0 + ts)) * 8 + (kt + 2)) * 64 + l];
        }
      }

      float mem_[2][4], out_[2][4];
#pragma unroll
      for (int ts = 0; ts < 2; ++ts)
#pragma unroll
        for (int r = 0; r < 4; ++r) {
          float I = aI[ts][r] + bu2f(rxi[ts][r]);
          float O = aO[ts][r] + bu2f(rxo[ts][r]);
          float Uv = aU[ts][r] + bu2f(rxu[ts][r]);
          float memv = sigf(I) * tanh_(Uv) + rgc[ts][r];
          float outv = sigf(O) * tanh_(memv);
          mem_[ts][r] = memv;
          out_[ts][r] = outv;
          o_lds[(4 * lq + r) * LDH + jj + ts * 16] = f2bu(outv);
        }
      __syncthreads();  // B2

      f32x4 aF[2] = {z4, z4};
#pragma unroll
      for (int kt = 0; kt < 8; ++kt) {
        uint4 av = *(const uint4*)&o_lds[lm * LDH + kt * 32 + lq * 8];
        s16x8 a = asv(av);
#pragma unroll
        for (int ts = 0; ts < 2; ++ts) {
          uint4 bv = wf4[((nt0 + ts) * 8 + kt) * 64 + l];
          aF[ts] = MFMA16(a, asv(bv), aF[ts]);
        }
      }

#pragma unroll
      for (int ts = 0; ts < 2; ++ts)
#pragma unroll
        for (int r = 0; r < 4; ++r) {
          unsigned nd_ = ndr[r];
          int tgt = nd_ & 255, par = (nd_ >> 8) & 255;
          int nb = (blk * 16 + 4 * lq + r) << 8;
          int j = jj + ts * 16;
          float AF = aF[ts][r] + bu2f(rxf[ts][r]);
          float gated = sigf(AF) * mem_[ts][r];
          if (nd_ & 0x10000u) X[((size_t)(nb + tgt) << 8) + j] = out_[ts][r];
          if (nd_ & 0x20000u) {
            X[((size_t)(nb + par) << 8) + j] = xold[ts][r] + out_[ts][r];
            gcs[((size_t)(nb + par) << 8) + j] = gold[ts][r] + gated;
          }
        }
      __syncthreads();  // B3
      cur4 = nxt4;
      cur_g = nxt_g;
    }
  }
}

extern "C" void kernel_launch(void* const* d_in, const int* in_sizes, int n_in,
                              void* d_out, int out_size, void* d_ws, size_t ws_size,
                              hipStream_t stream) {
  const float* inputs = (const float*)d_in[0];
  const int* parents  = (const int*)d_in[1];
  const int* post     = (const int*)d_in[2];
  const float* xw     = (const float*)d_in[3];
  const float* hf     = (const float*)d_in[4];
  const float* hiou   = (const float*)d_in[5];
  const float* bias   = (const float*)d_in[6];
  float* X = (float*)d_out;  // csh-then-hs buffer (fast path: hs only)

  // ws layout (~192.8 MiB):
  //   [0, 128 MiB)   fiou_xb bf16  (B*N*4U)
  //   +134217728     gcs fp32      (B*N*U)   64 MiB
  //   +201326592     wiouB bf16    384 KiB
  //   +201719808     wfB bf16      128 KiB
  //   +201850880     ndg u32       256 KiB
  char* ws = (char*)d_ws;
  bf16* fiou     = (bf16*)ws;
  float* gcs     = (float*)(ws + (size_t)134217728);
  bf16* wiouB    = (bf16*)(ws + (size_t)201326592);
  bf16* wfB      = (bf16*)(ws + (size_t)201719808);
  unsigned* ndg  = (unsigned*)(ws + (size_t)201850880);

  hipMemsetAsync(X, 0, (size_t)Bq * Nn * Uu * sizeof(float), stream);
  hipMemsetAsync(gcs, 0, (size_t)Bq * Nn * Uu * sizeof(float), stream);

  hipFuncSetAttribute(reinterpret_cast<const void*>(scan3),
                      hipFuncAttributeMaxDynamicSharedMemorySize, SCAN_LDS);

  prep_weights<<<1024, 256, 0, stream>>>(hiou, hf, wiouB, wfB);
  prep_nd<<<256, 256, 0, stream>>>(parents, post, ndg);
  xproj<<<(Bq * Nn) / 16, 256, 0, stream>>>(inputs, xw, bias, (bf16*)fiou);
  scan3<<<16, 512, SCAN_LDS, stream>>>((const unsigned short*)fiou,
                                       (const unsigned short*)wiouB,
                                       (const unsigned short*)wfB,
                                       ndg, X, gcs);
}

// Round 8
// 2872.661 us; speedup vs baseline: 1.1748x; 1.0060x over previous
//
#include <hip/hip_runtime.h>
#include <hip/hip_bf16.h>

#define Bq 256
#define Nn 256
#define Dd 256
#define Uu 256

using bf16 = __hip_bfloat16;

typedef __attribute__((ext_vector_type(8))) short s16x8;
typedef __attribute__((ext_vector_type(4))) float f32x4;

__device__ __forceinline__ float bu2f(unsigned short u) {
  return __uint_as_float(((unsigned)u) << 16);
}
__device__ __forceinline__ unsigned short f2bu(float f) {
  union { bf16 h; unsigned short u; } c; c.h = __float2bfloat16(f); return c.u;
}
__device__ __forceinline__ float sigf(float x) { return 1.0f / (1.0f + __expf(-x)); }
__device__ __forceinline__ float tanh_(float x) { return 2.0f / (1.0f + __expf(-2.0f * x)) - 1.0f; }
__device__ __forceinline__ s16x8 asv(uint4 x) {
  union { uint4 u; s16x8 v; } c; c.u = x; return c.v;
}
#define MFMA16(a, b, c) __builtin_amdgcn_mfma_f32_16x16x32_bf16(a, b, c, 0, 0, 0)

// ---- weight prep: build MFMA B-fragments (bf16) for wiou and wf ----
// wiouB layout: gate-major (g=0:i, g=1:o, g=2:u), 65536 elems (128 KB) per gate.
__global__ __launch_bounds__(256) void prep_weights(
    const float* __restrict__ hiou, const float* __restrict__ hf,
    bf16* __restrict__ wiouB, bf16* __restrict__ wfB) {
  int idx = blockIdx.x * 256 + threadIdx.x;  // 262144 total
  int e = idx & 7, l = (idx >> 3) & 63, kt = (idx >> 9) & 7;
  int k = kt * 32 + (l >> 4) * 8 + e;
  if (idx < 196608) {
    int nt = (idx >> 12) & 15, g = idx >> 16;
    wiouB[idx] = __float2bfloat16(hiou[k * 768 + g * 256 + nt * 16 + (l & 15)]);
  } else {
    int t = idx - 196608;
    int nt = (t >> 12) & 15;
    wfB[t] = __float2bfloat16(hf[k * 256 + nt * 16 + (l & 15)]);
  }
}

// ---- node-info table: nd[blk][t][m] = tgt | par<<8 | om<<16 | pm<<17 ----
__global__ __launch_bounds__(256) void prep_nd(
    const int* __restrict__ parents, const int* __restrict__ post,
    unsigned* __restrict__ ndg) {
  int idx = blockIdx.x * 256 + threadIdx.x;  // 65536
  int b = idx >> 8, t = idx & 255;
  int po = post[b * 256 + t];
  int om = po >= 0;
  int tgt = om ? po : 0;
  int praw = parents[b * 256 + tgt];
  int pm = (praw >= 0) && om;
  int par = praw >= 0 ? praw : 0;
  unsigned word = (unsigned)(tgt & 255) | ((unsigned)(par & 255) << 8) |
                  ((unsigned)om << 16) | ((unsigned)pm << 17);
  ndg[(b >> 4) * 4096 + t * 16 + (b & 15)] = word;
}

// ---- phase 1: fiou_xb = inputs @ x_fiou + bias (unchanged this round) ----
__global__ __launch_bounds__(256) void xproj(
    const float* __restrict__ x, const float* __restrict__ w,
    const float* __restrict__ bias, bf16* __restrict__ out) {
  __shared__ float xs[Dd][16];
  const int tid = threadIdx.x;
  const int row0 = blockIdx.x * 16;
  for (int i = 0; i < 16; ++i) {
    int idx = i * 256 + tid;
    int r = idx >> 8, k = idx & 255;
    xs[k][r] = x[(size_t)(row0 + r) * Dd + k];
  }
  __syncthreads();
  const int c0 = tid * 4;
  float4 bv = *(const float4*)(bias + c0);
  float acc[16][4];
#pragma unroll
  for (int r = 0; r < 16; ++r) {
    acc[r][0] = bv.x; acc[r][1] = bv.y; acc[r][2] = bv.z; acc[r][3] = bv.w;
  }
  for (int k = 0; k < Dd; ++k) {
    float4 wv = *(const float4*)(w + (size_t)k * 1024 + c0);
    const float4* xr = (const float4*)xs[k];
    float4 x0 = xr[0], x1 = xr[1], x2 = xr[2], x3 = xr[3];
    float xv[16] = {x0.x, x0.y, x0.z, x0.w, x1.x, x1.y, x1.z, x1.w,
                    x2.x, x2.y, x2.z, x2.w, x3.x, x3.y, x3.z, x3.w};
#pragma unroll
    for (int r = 0; r < 16; ++r) {
      acc[r][0] += xv[r] * wv.x;
      acc[r][1] += xv[r] * wv.y;
      acc[r][2] += xv[r] * wv.z;
      acc[r][3] += xv[r] * wv.w;
    }
  }
#pragma unroll
  for (int r = 0; r < 16; ++r) {
    union { ushort4 u4; bf16 b[4]; } pk;
    pk.b[0] = __float2bfloat16(acc[r][0]);
    pk.b[1] = __float2bfloat16(acc[r][1]);
    pk.b[2] = __float2bfloat16(acc[r][2]);
    pk.b[3] = __float2bfloat16(acc[r][3]);
    *(ushort4*)(&out[(size_t)(row0 + r) * 1024 + c0]) = pk.u4;
  }
}

// ---- phase 2: MFMA scan, FULLY RESIDENT weights ----
// 16 blocks x 512 threads (8 waves). Block owns 16 batches (M=16).
// Diagnosis (r2/r5/r7 all ~9us/step; dispatch-0 same dur at 5x lower busy%):
// step time is WALL-LATENCY-bound by the per-step weight re-stream (ring
// distance 2 << L2 latency => ~8 serialized round trips/step). Weight
// addresses are t-invariant, so the stream reloads identical values.
// Fix: FULL residency. B-frags are lane-distributed (8KB/wave/gate-tile),
// so 8 waves x 192 regs = 384KB holds o+u+f in the register file with no
// duplication; i-gate lives in LDS (128KB). Zero VMEM in the MFMA loops.
#define LDH 264
#define SCAN_LDS (131072 + 2 * 16 * LDH * 2)
extern __shared__ char smem[];

__global__ __launch_bounds__(512, 2) void scan3(
    const unsigned short* __restrict__ fiou, const unsigned short* __restrict__ wiouB,
    const unsigned short* __restrict__ wfB, const unsigned* __restrict__ ndg,
    float* __restrict__ X, float* __restrict__ gcs) {
  unsigned short* i_lds = (unsigned short*)smem;            // 65536 elems: i-gate frags
  unsigned short* h_lds = (unsigned short*)(smem + 131072); // 16 x LDH
  unsigned short* o_lds = h_lds + 16 * LDH;                 // 16 x LDH
  __shared__ int okf;

  const int tid = threadIdx.x;
  const int w = tid >> 6, l = tid & 63;
  const int lm = l & 15, lq = l >> 4;
  const int blk = blockIdx.x;
  const int jj = 32 * w + lm;
  const int nt0 = 2 * w;  // wave's first col-tile

  if (tid == 0) okf = 1;
  const uint4* wp  = (const uint4*)wiouB;
  const uint4* wf4 = (const uint4*)wfB;
  // stage i-gate (g=0 = first 8192 uint4 of wiouB) into LDS
  {
    uint4* d = (uint4*)i_lds;
    for (int i = tid; i < 8192; i += 512) d[i] = wp[i];
  }
  const unsigned* ndb = ndg + blk * 4096;
  const uint4* ndb4 = (const uint4*)ndb;
  uint4 cur4 = ndb4[lq];
  unsigned cur_g = ndb[tid >> 5];
  __syncthreads();  // okf init visible

  // chain check: ndb[t*16+m] must equal t | (t+1)<<8 | om|pm pattern
  {
    int bad = 0;
#pragma unroll
    for (int k2 = 0; k2 < 8; ++k2) {
      int i = tid + 512 * k2;
      int tt = i >> 4;
      unsigned exp_ = (tt < 255)
          ? ((unsigned)tt | ((unsigned)(tt + 1) << 8) | 0x30000u)
          : (255u | 0x10000u);
      if (ndb[i] != exp_) bad = 1;
    }
    if (bad) atomicAnd(&okf, 0);
  }
  __syncthreads();  // okf final + i_lds staged
  const bool fast = (okf != 0);

  if (fast) {
    // ---------------- FAST PATH (chain) ----------------
    // o-gate (g=1), u-gate (g=2), wf fragments -> registers, loaded ONCE.
    // 48 uint4 = 192 regs/wave; lane-distributed, no duplication in block.
    uint4 wor[2][8], wur[2][8], wfr[2][8];
#pragma unroll
    for (int ts = 0; ts < 2; ++ts)
#pragma unroll
      for (int kt = 0; kt < 8; ++kt) {
        wor[ts][kt] = wp[((16 + (nt0 + ts)) * 8 + kt) * 64 + l];
        wur[ts][kt] = wp[((32 + (nt0 + ts)) * 8 + kt) * 64 + l];
        wfr[ts][kt] = wf4[((nt0 + ts) * 8 + kt) * 64 + l];
      }
    // zero initial h buffer (csh of first targets = 0)
    for (int i = tid; i < 16 * LDH; i += 512) h_lds[i] = 0;
    float gc_[2][4] = {{0.f, 0.f, 0.f, 0.f}, {0.f, 0.f, 0.f, 0.f}};

    // fiou rows for t=0 (tgt=0, par=1)
    unsigned short rxi[2][4], rxo[2][4], rxu[2][4], rxf[2][4];
#pragma unroll
    for (int r = 0; r < 4; ++r) {
      int nb = (blk * 16 + 4 * lq + r) << 8;
      const unsigned short* fT = fiou + ((size_t)(nb + 0) << 10);
      const unsigned short* fP = fiou + ((size_t)(nb + 1) << 10);
#pragma unroll
      for (int ts = 0; ts < 2; ++ts) {
        int j = jj + ts * 16;
        rxi[ts][r] = fT[256 + j];
        rxo[ts][r] = fT[512 + j];
        rxu[ts][r] = fT[768 + j];
        rxf[ts][r] = fP[j];
      }
    }
    __syncthreads();  // h zero visible

    unsigned short* obA = h_lds;  // holds out_{t-1} == h_t
    unsigned short* obW = o_lds;  // receives out_t
    const uint4* il4 = (const uint4*)i_lds;
    const f32x4 z4 = {0.f, 0.f, 0.f, 0.f};

    for (int t = 0; t < Nn; ++t) {
      // iou MFMA: h(16x256) @ [i|o|u]; i from LDS, o/u from regs. NO VMEM.
      f32x4 aI[2] = {z4, z4}, aO[2] = {z4, z4}, aU[2] = {z4, z4};
#pragma unroll
      for (int kt = 0; kt < 8; ++kt) {
        uint4 av = *(const uint4*)&obA[lm * LDH + kt * 32 + lq * 8];
        s16x8 a = asv(av);
#pragma unroll
        for (int ts = 0; ts < 2; ++ts) {
          aI[ts] = MFMA16(a, asv(il4[((nt0 + ts) * 8 + kt) * 64 + l]), aI[ts]);
          aO[ts] = MFMA16(a, asv(wor[ts][kt]), aO[ts]);
          aU[ts] = MFMA16(a, asv(wur[ts][kt]), aU[ts]);
        }
      }

      // gating (gcs[tgt] is the register carry gc_); obW write + hs store.
      // mem_/out_ reuse the register space freed by aI/aO/aU.
      float mem_[2][4], out_[2][4];
#pragma unroll
      for (int ts = 0; ts < 2; ++ts)
#pragma unroll
        for (int r = 0; r < 4; ++r) {
          float I = aI[ts][r] + bu2f(rxi[ts][r]);
          float O = aO[ts][r] + bu2f(rxo[ts][r]);
          float Uv = aU[ts][r] + bu2f(rxu[ts][r]);
          float memv = sigf(I) * tanh_(Uv) + gc_[ts][r];
          float outv = sigf(O) * tanh_(memv);
          mem_[ts][r] = memv;
          out_[ts][r] = outv;
          obW[(4 * lq + r) * LDH + jj + ts * 16] = f2bu(outv);
          int nb = (blk * 16 + 4 * lq + r) << 8;
          X[((size_t)(nb + t) << 8) + jj + ts * 16] = outv;
        }
      __syncthreads();  // obW (= out_t) ready; X store drain mostly covered

      // fiou iou-gate prefetch for t+1: issued HERE (a full step of cover
      // before consumption at t+1's gating; drains at next barrier).
      {
        int tgtN = (t < Nn - 1) ? t + 1 : t;  // clamped; last iter unused
#pragma unroll
        for (int r = 0; r < 4; ++r) {
          int nb = (blk * 16 + 4 * lq + r) << 8;
          const unsigned short* fT = fiou + ((size_t)(nb + tgtN) << 10);
#pragma unroll
          for (int ts = 0; ts < 2; ++ts) {
            int j = jj + ts * 16;
            rxi[ts][r] = fT[256 + j];
            rxo[ts][r] = fT[512 + j];
            rxu[ts][r] = fT[768 + j];
          }
        }
      }

      // f MFMA: out(16x256) @ wf(256x256), wf frags register-resident
      f32x4 aF[2] = {z4, z4};
#pragma unroll
      for (int kt = 0; kt < 8; ++kt) {
        uint4 av = *(const uint4*)&obW[lm * LDH + kt * 32 + lq * 8];
        s16x8 a = asv(av);
#pragma unroll
        for (int ts = 0; ts < 2; ++ts)
          aF[ts] = MFMA16(a, asv(wfr[ts][kt]), aF[ts]);
      }

      // carry update: gcs[par=t+1] = gated_t (register, same thread owns it)
#pragma unroll
      for (int ts = 0; ts < 2; ++ts)
#pragma unroll
        for (int r = 0; r < 4; ++r) {
          float AF = aF[ts][r] + bu2f(rxf[ts][r]);
          gc_[ts][r] = sigf(AF) * mem_[ts][r];
        }

      // f-gate prefetch for t+1 (AFTER rxf's last use above)
      {
        int tgtN = (t < Nn - 1) ? t + 1 : t;
        int parN = (tgtN < 255) ? tgtN + 1 : 0;
#pragma unroll
        for (int r = 0; r < 4; ++r) {
          int nb = (blk * 16 + 4 * lq + r) << 8;
          const unsigned short* fP = fiou + ((size_t)(nb + parN) << 10);
#pragma unroll
          for (int ts = 0; ts < 2; ++ts)
            rxf[ts][r] = fP[jj + ts * 16];
        }
      }

      // ping-pong: out_t becomes h_{t+1}
      unsigned short* tmp = obA; obA = obW; obW = tmp;
    }
  } else {
    // ---------------- SLOW PATH (general trees; as round-7 verified) ----
    for (int t = 0; t < Nn; ++t) {
      const int r16 = tid >> 5, c8 = (tid & 31) * 8;
      int nrh = ((blk * 16 + r16) << 8) + (int)(cur_g & 255);
      const float* xr = X + ((size_t)nrh << 8) + c8;
      float4 a0 = ((const float4*)xr)[0];
      float4 a1 = ((const float4*)xr)[1];

      unsigned ndr[4] = {cur4.x, cur4.y, cur4.z, cur4.w};

      unsigned short rxi[2][4], rxo[2][4], rxu[2][4], rxf[2][4];
      float rgc[2][4], xold[2][4], gold[2][4];
#pragma unroll
      for (int r = 0; r < 4; ++r) {
        int tgt = ndr[r] & 255, par = (ndr[r] >> 8) & 255;
        int nb = (blk * 16 + 4 * lq + r) << 8;
        int nrT = nb + tgt, nrP = nb + par;
        const unsigned short* fT = fiou + ((size_t)nrT << 10);
        const unsigned short* fP = fiou + ((size_t)nrP << 10);
#pragma unroll
        for (int ts = 0; ts < 2; ++ts) {
          int j = jj + ts * 16;
          rxi[ts][r] = fT[256 + j];
          rxo[ts][r] = fT[512 + j];
          rxu[ts][r] = fT[768 + j];
          rxf[ts][r] = fP[j];
          rgc[ts][r]  = gcs[((size_t)nrT << 8) + j];
          xold[ts][r] = X[((size_t)nrP << 8) + j];
          gold[ts][r] = gcs[((size_t)nrP << 8) + j];
        }
      }

      uint4 st2[2][3][2];
#pragma unroll
      for (int g = 0; g < 3; ++g)
#pragma unroll
        for (int ts = 0; ts < 2; ++ts) {
          st2[0][g][ts] = wp[((g * 16 + (nt0 + ts)) * 8 + 0) * 64 + l];
          st2[1][g][ts] = wp[((g * 16 + (nt0 + ts)) * 8 + 1) * 64 + l];
        }

      {
        ushort4 p0, p1;
        p0.x = f2bu(a0.x); p0.y = f2bu(a0.y); p0.z = f2bu(a0.z); p0.w = f2bu(a0.w);
        p1.x = f2bu(a1.x); p1.y = f2bu(a1.y); p1.z = f2bu(a1.z); p1.w = f2bu(a1.w);
        *(ushort4*)&h_lds[r16 * LDH + c8] = p0;
        *(ushort4*)&h_lds[r16 * LDH + c8 + 4] = p1;
      }
      __syncthreads();  // B1

      const int tn = t < Nn - 1 ? t + 1 : t;
      uint4 nxt4 = ndb4[tn * 4 + lq];
      unsigned nxt_g = ndb[tn * 16 + (tid >> 5)];

      f32x4 z4 = {0.f, 0.f, 0.f, 0.f};
      f32x4 aI[2] = {z4, z4}, aO[2] = {z4, z4}, aU[2] = {z4, z4};
#pragma unroll
      for (int kt = 0; kt < 8; ++kt) {
        uint4 av = *(const uint4*)&h_lds[lm * LDH + kt * 32 + lq * 8];
        s16x8 a = asv(av);
#pragma unroll
        for (int ts = 0; ts < 2; ++ts) {
          aI[ts] = MFMA16(a, asv(st2[kt & 1][0][ts]), aI[ts]);
          aO[ts] = MFMA16(a, asv(st2[kt & 1][1][ts]), aO[ts]);
          aU[ts] = MFMA16(a, asv(st2[kt & 1][2][ts]), aU[ts]);
        }
        if (kt < 6) {
#pragma unroll
          for (int g = 0; g < 3; ++g)
#pragma unroll
            for (int ts = 0; ts < 2; ++ts)
              st2[kt & 1][g][ts] = wp[((g * 16 + (nt0 + ts)) * 8 + (kt + 2)) * 64 + l];
        }
      }

      float mem_[2][4], out_[2][4];
#pragma unroll
      for (int ts = 0; ts < 2; ++ts)
#pragma unroll
        for (int r = 0; r < 4; ++r) {
          float I = aI[ts][r] + bu2f(rxi[ts][r]);
          float O = aO[ts][r] + bu2f(rxo[ts][r]);
          float Uv = aU[ts][r] + bu2f(rxu[ts][r]);
          float memv = sigf(I) * tanh_(Uv) + rgc[ts][r];
          float outv = sigf(O) * tanh_(memv);
          mem_[ts][r] = memv;
          out_[ts][r] = outv;
          o_lds[(4 * lq + r) * LDH + jj + ts * 16] = f2bu(outv);
        }
      __syncthreads();  // B2

      f32x4 aF[2] = {z4, z4};
#pragma unroll
      for (int kt = 0; kt < 8; ++kt) {
        uint4 av = *(const uint4*)&o_lds[lm * LDH + kt * 32 + lq * 8];
        s16x8 a = asv(av);
#pragma unroll
        for (int ts = 0; ts < 2; ++ts) {
          uint4 bv = wf4[((nt0 + ts) * 8 + kt) * 64 + l];
          aF[ts] = MFMA16(a, asv(bv), aF[ts]);
        }
      }

#pragma unroll
      for (int ts = 0; ts < 2; ++ts)
#pragma unroll
        for (int r = 0; r < 4; ++r) {
          unsigned nd_ = ndr[r];
          int tgt = nd_ & 255, par = (nd_ >> 8) & 255;
          int nb = (blk * 16 + 4 * lq + r) << 8;
          int j = jj + ts * 16;
          float AF = aF[ts][r] + bu2f(rxf[ts][r]);
          float gated = sigf(AF) * mem_[ts][r];
          if (nd_ & 0x10000u) X[((size_t)(nb + tgt) << 8) + j] = out_[ts][r];
          if (nd_ & 0x20000u) {
            X[((size_t)(nb + par) << 8) + j] = xold[ts][r] + out_[ts][r];
            gcs[((size_t)(nb + par) << 8) + j] = gold[ts][r] + gated;
          }
        }
      __syncthreads();  // B3
      cur4 = nxt4;
      cur_g = nxt_g;
    }
  }
}

extern "C" void kernel_launch(void* const* d_in, const int* in_sizes, int n_in,
                              void* d_out, int out_size, void* d_ws, size_t ws_size,
                              hipStream_t stream) {
  const float* inputs = (const float*)d_in[0];
  const int* parents  = (const int*)d_in[1];
  const int* post     = (const int*)d_in[2];
  const float* xw     = (const float*)d_in[3];
  const float* hf     = (const float*)d_in[4];
  const float* hiou   = (const float*)d_in[5];
  const float* bias   = (const float*)d_in[6];
  float* X = (float*)d_out;  // csh-then-hs buffer (fast path: hs only)

  // ws layout (~192.8 MiB):
  //   [0, 128 MiB)   fiou_xb bf16  (B*N*4U)
  //   +134217728     gcs fp32      (B*N*U)   64 MiB
  //   +201326592     wiouB bf16    384 KiB
  //   +201719808     wfB bf16      128 KiB
  //   +201850880     ndg u32       256 KiB
  char* ws = (char*)d_ws;
  bf16* fiou     = (bf16*)ws;
  float* gcs     = (float*)(ws + (size_t)134217728);
  bf16* wiouB    = (bf16*)(ws + (size_t)201326592);
  bf16* wfB      = (bf16*)(ws + (size_t)201719808);
  unsigned* ndg  = (unsigned*)(ws + (size_t)201850880);

  hipMemsetAsync(X, 0, (size_t)Bq * Nn * Uu * sizeof(float), stream);
  hipMemsetAsync(gcs, 0, (size_t)Bq * Nn * Uu * sizeof(float), stream);

  hipFuncSetAttribute(reinterpret_cast<const void*>(scan3),
                      hipFuncAttributeMaxDynamicSharedMemorySize, SCAN_LDS);

  prep_weights<<<1024, 256, 0, stream>>>(hiou, hf, wiouB, wfB);
  prep_nd<<<256, 256, 0, stream>>>(parents, post, ndg);
  xproj<<<(Bq * Nn) / 16, 256, 0, stream>>>(inputs, xw, bias, (bf16*)fiou);
  scan3<<<16, 512, SCAN_LDS, stream>>>((const unsigned short*)fiou,
                                       (const unsigned short*)wiouB,
                                       (const unsigned short*)wfB,
                                       ndg, X, gcs);
}

// Round 10
// 2242.166 us; speedup vs baseline: 1.5051x; 1.2812x over previous
//
#include <hip/hip_runtime.h>
#include <hip/hip_bf16.h>

#define Bq 256
#define Nn 256
#define Dd 256
#define Uu 256

using bf16 = __hip_bfloat16;

typedef __attribute__((ext_vector_type(8))) short s16x8;
typedef __attribute__((ext_vector_type(4))) float f32x4;

__device__ __forceinline__ float bu2f(unsigned short u) {
  return __uint_as_float(((unsigned)u) << 16);
}
__device__ __forceinline__ unsigned short f2bu(float f) {
  union { bf16 h; unsigned short u; } c; c.h = __float2bfloat16(f); return c.u;
}
__device__ __forceinline__ float sigf(float x) { return 1.0f / (1.0f + __expf(-x)); }
__device__ __forceinline__ float tanh_(float x) { return 2.0f / (1.0f + __expf(-2.0f * x)) - 1.0f; }
__device__ __forceinline__ s16x8 asv(uint4 x) {
  union { uint4 u; s16x8 v; } c; c.u = x; return c.v;
}
#define MFMA16(a, b, c) __builtin_amdgcn_mfma_f32_16x16x32_bf16(a, b, c, 0, 0, 0)

// ---- weight prep: build MFMA B-fragments (bf16) for wiou and wf ----
// wiouB layout: gate-major (g=0:i, g=1:o, g=2:u), 65536 elems (128 KB) per gate.
__global__ __launch_bounds__(256) void prep_weights(
    const float* __restrict__ hiou, const float* __restrict__ hf,
    bf16* __restrict__ wiouB, bf16* __restrict__ wfB) {
  int idx = blockIdx.x * 256 + threadIdx.x;  // 262144 total
  int e = idx & 7, l = (idx >> 3) & 63, kt = (idx >> 9) & 7;
  int k = kt * 32 + (l >> 4) * 8 + e;
  if (idx < 196608) {
    int nt = (idx >> 12) & 15, g = idx >> 16;
    wiouB[idx] = __float2bfloat16(hiou[k * 768 + g * 256 + nt * 16 + (l & 15)]);
  } else {
    int t = idx - 196608;
    int nt = (t >> 12) & 15;
    wfB[t] = __float2bfloat16(hf[k * 256 + nt * 16 + (l & 15)]);
  }
}

// ---- node-info table: nd[bgrp][t][m] = tgt | par<<8 | om<<16 | pm<<17 ----
__global__ __launch_bounds__(256) void prep_nd(
    const int* __restrict__ parents, const int* __restrict__ post,
    unsigned* __restrict__ ndg) {
  int idx = blockIdx.x * 256 + threadIdx.x;  // 65536
  int b = idx >> 8, t = idx & 255;
  int po = post[b * 256 + t];
  int om = po >= 0;
  int tgt = om ? po : 0;
  int praw = parents[b * 256 + tgt];
  int pm = (praw >= 0) && om;
  int par = praw >= 0 ? praw : 0;
  unsigned word = (unsigned)(tgt & 255) | ((unsigned)(par & 255) << 8) |
                  ((unsigned)om << 16) | ((unsigned)pm << 17);
  ndg[(b >> 4) * 4096 + t * 16 + (b & 15)] = word;
}

// ---- phase 1: fiou_xb = inputs @ x_fiou + bias (unchanged this round) ----
__global__ __launch_bounds__(256) void xproj(
    const float* __restrict__ x, const float* __restrict__ w,
    const float* __restrict__ bias, bf16* __restrict__ out) {
  __shared__ float xs[Dd][16];
  const int tid = threadIdx.x;
  const int row0 = blockIdx.x * 16;
  for (int i = 0; i < 16; ++i) {
    int idx = i * 256 + tid;
    int r = idx >> 8, k = idx & 255;
    xs[k][r] = x[(size_t)(row0 + r) * Dd + k];
  }
  __syncthreads();
  const int c0 = tid * 4;
  float4 bv = *(const float4*)(bias + c0);
  float acc[16][4];
#pragma unroll
  for (int r = 0; r < 16; ++r) {
    acc[r][0] = bv.x; acc[r][1] = bv.y; acc[r][2] = bv.z; acc[r][3] = bv.w;
  }
  for (int k = 0; k < Dd; ++k) {
    float4 wv = *(const float4*)(w + (size_t)k * 1024 + c0);
    const float4* xr = (const float4*)xs[k];
    float4 x0 = xr[0], x1 = xr[1], x2 = xr[2], x3 = xr[3];
    float xv[16] = {x0.x, x0.y, x0.z, x0.w, x1.x, x1.y, x1.z, x1.w,
                    x2.x, x2.y, x2.z, x2.w, x3.x, x3.y, x3.z, x3.w};
#pragma unroll
    for (int r = 0; r < 16; ++r) {
      acc[r][0] += xv[r] * wv.x;
      acc[r][1] += xv[r] * wv.y;
      acc[r][2] += xv[r] * wv.z;
      acc[r][3] += xv[r] * wv.w;
    }
  }
#pragma unroll
  for (int r = 0; r < 16; ++r) {
    union { ushort4 u4; bf16 b[4]; } pk;
    pk.b[0] = __float2bfloat16(acc[r][0]);
    pk.b[1] = __float2bfloat16(acc[r][1]);
    pk.b[2] = __float2bfloat16(acc[r][2]);
    pk.b[3] = __float2bfloat16(acc[r][3]);
    *(ushort4*)(&out[(size_t)(row0 + r) * 1024 + c0]) = pk.u4;
  }
}

// ---- phase 2: MFMA scan, M=1 (one batch per block, 256 blocks) ----
// Diagnosis (r2..r8 all ~9us/step on 16 CUs; dispatch-0 same dur at 5x
// lower busy% => clock-independent): per-step cost is per-CU memory-PIPE
// throughput (16-batch scalar fiou gather = 256 VMEM instr/CU/step) plus
// weight/scratch refill traffic; 192 weight-regs did NOT fit at M=16
// (VGPR=128 + spill => r8 == r7). At M=1 the per-CU gather is 16x smaller
// and per-wave state ~60 regs, so o+u+f (192 regs) are genuinely resident
// and i sits in LDS: ZERO weight traffic in the loop, 1 barrier/step.
#define LDH 264
#define SCAN_LDS (131072 + 2 * 16 * LDH * 2)
extern __shared__ char smem[];

__global__ __launch_bounds__(512, 2) void scan3(
    const unsigned short* __restrict__ fiou, const unsigned short* __restrict__ wiouB,
    const unsigned short* __restrict__ wfB, const unsigned* __restrict__ ndg,
    float* __restrict__ X, float* __restrict__ gcs) {
  unsigned short* i_lds = (unsigned short*)smem;            // 65536 elems: i-gate frags
  unsigned short* h_lds = (unsigned short*)(smem + 131072); // 16 x LDH (rows 1-15 stay 0)
  unsigned short* o_lds = h_lds + 16 * LDH;                 // 16 x LDH (rows 1-15 stay 0)
  __shared__ int okf;

  const int tid = threadIdx.x;
  const int w = tid >> 6, l = tid & 63;
  const int lm = l & 15, lq = l >> 4;
  const int b = blockIdx.x;          // one batch per block
  const int jj = 32 * w + lm;        // this lane's column (ts adds +16)
  const int nt0 = 2 * w;             // wave's first col-tile
  const bool act = (lq == 0);        // lanes owning row 0 of the C tile

  if (tid == 0) okf = 1;
  const uint4* wp  = (const uint4*)wiouB;
  const uint4* wf4 = (const uint4*)wfB;
  // stage i-gate into LDS
  {
    uint4* d = (uint4*)i_lds;
    for (int i = tid; i < 8192; i += 512) d[i] = wp[i];
  }
  // zero h/o buffers (rows 1-15 must be zero: A rows beyond M=1)
  for (int i = tid; i < 2 * 16 * LDH; i += 512) h_lds[i] = 0;
  // o,u,f weights -> registers (48 uint4 = 192 regs/wave, resident)
  uint4 wor[2][8], wur[2][8], wfr[2][8];
#pragma unroll
  for (int ts = 0; ts < 2; ++ts)
#pragma unroll
    for (int kt = 0; kt < 8; ++kt) {
      wor[ts][kt] = wp[((16 + (nt0 + ts)) * 8 + kt) * 64 + l];
      wur[ts][kt] = wp[((32 + (nt0 + ts)) * 8 + kt) * 64 + l];
      wfr[ts][kt] = wf4[((nt0 + ts) * 8 + kt) * 64 + l];
    }
  const unsigned* ndb = ndg + (b >> 4) * 4096 + (b & 15);  // stride 16 per t
  __syncthreads();  // okf init + i_lds + zeros visible

  // chain check for THIS batch: word(t) == t | (t+1)<<8 | om|pm
  if (tid < 256) {
    unsigned exp_ = (tid < 255)
        ? ((unsigned)tid | ((unsigned)(tid + 1) << 8) | 0x30000u)
        : (255u | 0x10000u);
    if (ndb[tid * 16] != exp_) atomicAnd(&okf, 0);
  }
  __syncthreads();

  const uint4* il4 = (const uint4*)i_lds;
  const f32x4 z4 = {0.f, 0.f, 0.f, 0.f};
  const size_t fb = ((size_t)b) << 18;  // fiou elems: b*256*1024
  const size_t xb = ((size_t)b) << 16;  // X/gcs elems: b*256*256

  if (okf != 0) {
    // ---------------- FAST PATH (chain, M=1) ----------------
    unsigned short* obA = h_lds;  // holds out_{t-1} (row 0)
    unsigned short* obW = o_lds;  // receives out_t  (row 0)
    float gc_[2] = {0.f, 0.f};
    unsigned short rxi[2], rxo[2], rxu[2], rxf[2];
    if (act) {
#pragma unroll
      for (int ts = 0; ts < 2; ++ts) {
        int j = jj + ts * 16;
        rxi[ts] = fiou[fb + 256 + j];        // row 0 (tgt=0)
        rxo[ts] = fiou[fb + 512 + j];
        rxu[ts] = fiou[fb + 768 + j];
        rxf[ts] = fiou[fb + 1024 + j];       // row 1 (par=1), f slice
      }
    }

    for (int t = 0; t < Nn; ++t) {
      // 1) iou MFMA: h(1x256) @ [i|o|u]; i from LDS, o/u from regs. NO VMEM.
      f32x4 aI[2] = {z4, z4}, aO[2] = {z4, z4}, aU[2] = {z4, z4};
#pragma unroll
      for (int kt = 0; kt < 8; ++kt) {
        uint4 av = *(const uint4*)&obA[lm * LDH + kt * 32 + lq * 8];
        s16x8 a = asv(av);
#pragma unroll
        for (int ts = 0; ts < 2; ++ts) {
          aI[ts] = MFMA16(a, asv(il4[((nt0 + ts) * 8 + kt) * 64 + l]), aI[ts]);
          aO[ts] = MFMA16(a, asv(wor[ts][kt]), aO[ts]);
          aU[ts] = MFMA16(a, asv(wur[ts][kt]), aU[ts]);
        }
      }

      // 2) gating (row 0 = act lanes, acc reg 0); obW row0 + hs store
      float mem_[2], out_[2];
      if (act) {
#pragma unroll
        for (int ts = 0; ts < 2; ++ts) {
          float I  = aI[ts][0] + bu2f(rxi[ts]);
          float O  = aO[ts][0] + bu2f(rxo[ts]);
          float Uv = aU[ts][0] + bu2f(rxu[ts]);
          float memv = sigf(I) * tanh_(Uv) + gc_[ts];
          float outv = sigf(O) * tanh_(memv);
          mem_[ts] = memv;
          out_[ts] = outv;
          obW[jj + ts * 16] = f2bu(outv);
          X[xb + (size_t)t * 256 + jj + ts * 16] = outv;
        }
      }
      __syncthreads();  // obW (= out_t) ready; doubles as h_{t+1}

      // 3) prefetch t+1 iou gates (full step of cover)
      const int tgtN = (t < Nn - 1) ? t + 1 : t;
      if (act) {
        size_t fr = fb + (size_t)tgtN * 1024;
#pragma unroll
        for (int ts = 0; ts < 2; ++ts) {
          int j = jj + ts * 16;
          rxi[ts] = fiou[fr + 256 + j];
          rxo[ts] = fiou[fr + 512 + j];
          rxu[ts] = fiou[fr + 768 + j];
        }
      }

      // 4) f MFMA: out(1x256) @ wf, wf register-resident
      f32x4 aF[2] = {z4, z4};
#pragma unroll
      for (int kt = 0; kt < 8; ++kt) {
        uint4 av = *(const uint4*)&obW[lm * LDH + kt * 32 + lq * 8];
        s16x8 a = asv(av);
#pragma unroll
        for (int ts = 0; ts < 2; ++ts)
          aF[ts] = MFMA16(a, asv(wfr[ts][kt]), aF[ts]);
      }

      // 5) carry update + 6) rxf prefetch for t+1
      if (act) {
#pragma unroll
        for (int ts = 0; ts < 2; ++ts) {
          float AF = aF[ts][0] + bu2f(rxf[ts]);
          gc_[ts] = sigf(AF) * mem_[ts];
        }
        int parN = (tgtN < 255) ? tgtN + 1 : 0;
        size_t fp = fb + (size_t)parN * 1024;
#pragma unroll
        for (int ts = 0; ts < 2; ++ts)
          rxf[ts] = fiou[fp + jj + ts * 16];
      }

      // ping-pong: out_t becomes h_{t+1}
      unsigned short* tmp = obA; obA = obW; obW = tmp;
    }
  } else {
    // ---------------- SLOW PATH (general tree, M=1) ----------------
    for (int t = 0; t < Nn; ++t) {
      unsigned nd_ = ndb[t * 16];
      int tgt = nd_ & 255, par = (nd_ >> 8) & 255;

      // h-gather: csh row (X[tgt]) -> bf16 -> h_lds row 0
      if (tid < 256)
        h_lds[tid] = f2bu(X[xb + (size_t)tgt * 256 + tid]);

      unsigned short rxi[2], rxo[2], rxu[2], rxf[2];
      float rgc[2], xold[2], gold[2];
      if (act) {
        size_t ft = fb + (size_t)tgt * 1024;
        size_t fp = fb + (size_t)par * 1024;
#pragma unroll
        for (int ts = 0; ts < 2; ++ts) {
          int j = jj + ts * 16;
          rxi[ts] = fiou[ft + 256 + j];
          rxo[ts] = fiou[ft + 512 + j];
          rxu[ts] = fiou[ft + 768 + j];
          rxf[ts] = fiou[fp + j];
          rgc[ts]  = gcs[xb + (size_t)tgt * 256 + j];
          xold[ts] = X[xb + (size_t)par * 256 + j];
          gold[ts] = gcs[xb + (size_t)par * 256 + j];
        }
      }
      __syncthreads();  // h row ready

      f32x4 aI[2] = {z4, z4}, aO[2] = {z4, z4}, aU[2] = {z4, z4};
#pragma unroll
      for (int kt = 0; kt < 8; ++kt) {
        uint4 av = *(const uint4*)&h_lds[lm * LDH + kt * 32 + lq * 8];
        s16x8 a = asv(av);
#pragma unroll
        for (int ts = 0; ts < 2; ++ts) {
          aI[ts] = MFMA16(a, asv(il4[((nt0 + ts) * 8 + kt) * 64 + l]), aI[ts]);
          aO[ts] = MFMA16(a, asv(wor[ts][kt]), aO[ts]);
          aU[ts] = MFMA16(a, asv(wur[ts][kt]), aU[ts]);
        }
      }

      float mem_[2], out_[2];
      if (act) {
#pragma unroll
        for (int ts = 0; ts < 2; ++ts) {
          float I  = aI[ts][0] + bu2f(rxi[ts]);
          float O  = aO[ts][0] + bu2f(rxo[ts]);
          float Uv = aU[ts][0] + bu2f(rxu[ts]);
          float memv = sigf(I) * tanh_(Uv) + rgc[ts];
          float outv = sigf(O) * tanh_(memv);
          mem_[ts] = memv;
          out_[ts] = outv;
          o_lds[jj + ts * 16] = f2bu(outv);
        }
      }
      __syncthreads();  // out row ready

      f32x4 aF[2] = {z4, z4};
#pragma unroll
      for (int kt = 0; kt < 8; ++kt) {
        uint4 av = *(const uint4*)&o_lds[lm * LDH + kt * 32 + lq * 8];
        s16x8 a = asv(av);
#pragma unroll
        for (int ts = 0; ts < 2; ++ts)
          aF[ts] = MFMA16(a, asv(wfr[ts][kt]), aF[ts]);
      }

      if (act) {
#pragma unroll
        for (int ts = 0; ts < 2; ++ts) {
          int j = jj + ts * 16;
          float AF = aF[ts][0] + bu2f(rxf[ts]);
          float gated = sigf(AF) * mem_[ts];
          if (nd_ & 0x10000u) X[xb + (size_t)tgt * 256 + j] = out_[ts];
          if (nd_ & 0x20000u) {
            X[xb + (size_t)par * 256 + j] = xold[ts] + out_[ts];
            gcs[xb + (size_t)par * 256 + j] = gold[ts] + gated;
          }
        }
      }
      __syncthreads();  // epilogue visible before next h-gather
    }
  }
}

extern "C" void kernel_launch(void* const* d_in, const int* in_sizes, int n_in,
                              void* d_out, int out_size, void* d_ws, size_t ws_size,
                              hipStream_t stream) {
  const float* inputs = (const float*)d_in[0];
  const int* parents  = (const int*)d_in[1];
  const int* post     = (const int*)d_in[2];
  const float* xw     = (const float*)d_in[3];
  const float* hf     = (const float*)d_in[4];
  const float* hiou   = (const float*)d_in[5];
  const float* bias   = (const float*)d_in[6];
  float* X = (float*)d_out;  // csh-then-hs buffer (fast path: hs only)

  // ws layout (~192.8 MiB):
  //   [0, 128 MiB)   fiou_xb bf16  (B*N*4U)
  //   +134217728     gcs fp32      (B*N*U)   64 MiB
  //   +201326592     wiouB bf16    384 KiB
  //   +201719808     wfB bf16      128 KiB
  //   +201850880     ndg u32       256 KiB
  char* ws = (char*)d_ws;
  bf16* fiou     = (bf16*)ws;
  float* gcs     = (float*)(ws + (size_t)134217728);
  bf16* wiouB    = (bf16*)(ws + (size_t)201326592);
  bf16* wfB      = (bf16*)(ws + (size_t)201719808);
  unsigned* ndg  = (unsigned*)(ws + (size_t)201850880);

  hipMemsetAsync(X, 0, (size_t)Bq * Nn * Uu * sizeof(float), stream);
  hipMemsetAsync(gcs, 0, (size_t)Bq * Nn * Uu * sizeof(float), stream);

  hipFuncSetAttribute(reinterpret_cast<const void*>(scan3),
                      hipFuncAttributeMaxDynamicSharedMemorySize, SCAN_LDS);

  prep_weights<<<1024, 256, 0, stream>>>(hiou, hf, wiouB, wfB);
  prep_nd<<<256, 256, 0, stream>>>(parents, post, ndg);
  xproj<<<(Bq * Nn) / 16, 256, 0, stream>>>(inputs, xw, bias, (bf16*)fiou);
  scan3<<<256, 512, SCAN_LDS, stream>>>((const unsigned short*)fiou,
                                        (const unsigned short*)wiouB,
                                        (const unsigned short*)wfB,
                                        ndg, X, gcs);
}

// Round 13
// 1644.398 us; speedup vs baseline: 2.0522x; 1.3635x over previous
//
#include <hip/hip_runtime.h>
#include <hip/hip_bf16.h>

#define Bq 256
#define Nn 256
#define Dd 256
#define Uu 256

using bf16 = __hip_bfloat16;

typedef __attribute__((ext_vector_type(8))) short s16x8;
typedef __attribute__((ext_vector_type(4))) float f32x4;

__device__ __forceinline__ float bu2f(unsigned short u) {
  return __uint_as_float(((unsigned)u) << 16);
}
__device__ __forceinline__ unsigned short f2bu(float f) {
  union { bf16 h; unsigned short u; } c; c.h = __float2bfloat16(f); return c.u;
}
__device__ __forceinline__ float sigf(float x) { return 1.0f / (1.0f + __expf(-x)); }
__device__ __forceinline__ float tanh_(float x) { return 2.0f / (1.0f + __expf(-2.0f * x)) - 1.0f; }
__device__ __forceinline__ s16x8 asv(uint4 x) {
  union { uint4 u; s16x8 v; } c; c.u = x; return c.v;
}
#define MFMA16(a, b, c) __builtin_amdgcn_mfma_f32_16x16x32_bf16(a, b, c, 0, 0, 0)

// ---- weight prep: build MFMA B-fragments (bf16) for wiou and wf ----
__global__ __launch_bounds__(256) void prep_weights(
    const float* __restrict__ hiou, const float* __restrict__ hf,
    bf16* __restrict__ wiouB, bf16* __restrict__ wfB) {
  int idx = blockIdx.x * 256 + threadIdx.x;  // 262144 total
  int e = idx & 7, l = (idx >> 3) & 63, kt = (idx >> 9) & 7;
  int k = kt * 32 + (l >> 4) * 8 + e;
  if (idx < 196608) {
    int nt = (idx >> 12) & 15, g = idx >> 16;
    wiouB[idx] = __float2bfloat16(hiou[k * 768 + g * 256 + nt * 16 + (l & 15)]);
  } else {
    int t = idx - 196608;
    int nt = (t >> 12) & 15;
    wfB[t] = __float2bfloat16(hf[k * 256 + nt * 16 + (l & 15)]);
  }
}

// ---- xw B-fragments, hi/lo split (for MFMA xproj) ----
__global__ __launch_bounds__(256) void prep_xw(
    const float* __restrict__ xw, bf16* __restrict__ xwHi, bf16* __restrict__ xwLo) {
  int idx = blockIdx.x * 256 + threadIdx.x;  // 262144
  int e = idx & 7, l = (idx >> 3) & 63, kt = (idx >> 9) & 7, nt = idx >> 12;
  int k = kt * 32 + (l >> 4) * 8 + e;
  float v = xw[k * 1024 + nt * 16 + (l & 15)];
  bf16 h = __float2bfloat16(v);
  xwHi[idx] = h;
  xwLo[idx] = __float2bfloat16(v - (float)h);
}

// ---- node-info table ----
__global__ __launch_bounds__(256) void prep_nd(
    const int* __restrict__ parents, const int* __restrict__ post,
    unsigned* __restrict__ ndg) {
  int idx = blockIdx.x * 256 + threadIdx.x;  // 65536
  int b = idx >> 8, t = idx & 255;
  int po = post[b * 256 + t];
  int om = po >= 0;
  int tgt = om ? po : 0;
  int praw = parents[b * 256 + tgt];
  int pm = (praw >= 0) && om;
  int par = praw >= 0 ? praw : 0;
  unsigned word = (unsigned)(tgt & 255) | ((unsigned)(par & 255) << 8) |
                  ((unsigned)om << 16) | ((unsigned)pm << 17);
  ndg[(b >> 4) * 4096 + t * 16 + (b & 15)] = word;
}

extern __shared__ char smem[];

// ---- phase 1 fallback: fp32 VALU xproj (used if ws too small) ----
__global__ __launch_bounds__(256) void xproj(
    const float* __restrict__ x, const float* __restrict__ w,
    const float* __restrict__ bias, bf16* __restrict__ out) {
  __shared__ float xs[Dd][16];
  const int tid = threadIdx.x;
  const int row0 = blockIdx.x * 16;
  for (int i = 0; i < 16; ++i) {
    int idx = i * 256 + tid;
    int r = idx >> 8, k = idx & 255;
    xs[k][r] = x[(size_t)(row0 + r) * Dd + k];
  }
  __syncthreads();
  const int c0 = tid * 4;
  float4 bv = *(const float4*)(bias + c0);
  float acc[16][4];
#pragma unroll
  for (int r = 0; r < 16; ++r) {
    acc[r][0] = bv.x; acc[r][1] = bv.y; acc[r][2] = bv.z; acc[r][3] = bv.w;
  }
  for (int k = 0; k < Dd; ++k) {
    float4 wv = *(const float4*)(w + (size_t)k * 1024 + c0);
    const float4* xr = (const float4*)xs[k];
    float4 x0 = xr[0], x1 = xr[1], x2 = xr[2], x3 = xr[3];
    float xv[16] = {x0.x, x0.y, x0.z, x0.w, x1.x, x1.y, x1.z, x1.w,
                    x2.x, x2.y, x2.z, x2.w, x3.x, x3.y, x3.z, x3.w};
#pragma unroll
    for (int r = 0; r < 16; ++r) {
      acc[r][0] += xv[r] * wv.x;
      acc[r][1] += xv[r] * wv.y;
      acc[r][2] += xv[r] * wv.z;
      acc[r][3] += xv[r] * wv.w;
    }
  }
#pragma unroll
  for (int r = 0; r < 16; ++r) {
    union { ushort4 u4; bf16 b[4]; } pk;
    pk.b[0] = __float2bfloat16(acc[r][0]);
    pk.b[1] = __float2bfloat16(acc[r][1]);
    pk.b[2] = __float2bfloat16(acc[r][2]);
    pk.b[3] = __float2bfloat16(acc[r][3]);
    *(ushort4*)(&out[(size_t)(row0 + r) * 1024 + c0]) = pk.u4;
  }
}

// ---- phase 1: MFMA xproj with hi/lo split (error ~ lo*lo ~ 1e-5, far
// below fiou's bf16 storage quantum -> absmax unchanged) ----
#define XP_LDS (2 * 64 * 264 * 2)
__global__ __launch_bounds__(512, 2) void xproj2(
    const float* __restrict__ x, const unsigned short* __restrict__ xwHi,
    const unsigned short* __restrict__ xwLo, const float* __restrict__ bias,
    unsigned short* __restrict__ out) {
  unsigned short* a_hi = (unsigned short*)smem;             // [64][264]
  unsigned short* a_lo = a_hi + 64 * 264;
  const int tid = threadIdx.x;
  const int w = tid >> 6, l = tid & 63;
  const int lm = l & 15, lq = l >> 4;
  const size_t row0 = (size_t)blockIdx.x * 64;

  // stage A rows -> hi/lo bf16 in LDS
  {
    int r = tid >> 3, c0 = (tid & 7) * 32;
    const float* src = x + (row0 + r) * 256 + c0;
#pragma unroll
    for (int c = 0; c < 32; c += 4) {
      float4 v = *(const float4*)(src + c);
      unsigned short h0 = f2bu(v.x), h1 = f2bu(v.y), h2 = f2bu(v.z), h3 = f2bu(v.w);
      ushort4 hv = {h0, h1, h2, h3};
      ushort4 lv = {f2bu(v.x - bu2f(h0)), f2bu(v.y - bu2f(h1)),
                    f2bu(v.z - bu2f(h2)), f2bu(v.w - bu2f(h3))};
      *(ushort4*)&a_hi[r * 264 + c0 + c] = hv;
      *(ushort4*)&a_lo[r * 264 + c0 + c] = lv;
    }
  }
  __syncthreads();

  const uint4* bh = (const uint4*)xwHi;
  const uint4* bl = (const uint4*)xwLo;
  f32x4 acc[8][4];
#pragma unroll
  for (int nt = 0; nt < 8; ++nt) {
    float b = bias[(w * 8 + nt) * 16 + lm];
#pragma unroll
    for (int rt = 0; rt < 4; ++rt) acc[nt][rt] = {b, b, b, b};
  }
  for (int kt = 0; kt < 8; ++kt) {
    uint4 Bh[8], Bl[8];
#pragma unroll
    for (int nt = 0; nt < 8; ++nt) {
      int f = ((w * 8 + nt) * 8 + kt) * 64 + l;
      Bh[nt] = bh[f];
      Bl[nt] = bl[f];
    }
    s16x8 Ah[4], Al[4];
#pragma unroll
    for (int rt = 0; rt < 4; ++rt) {
      Ah[rt] = asv(*(const uint4*)&a_hi[(rt * 16 + lm) * 264 + kt * 32 + lq * 8]);
      Al[rt] = asv(*(const uint4*)&a_lo[(rt * 16 + lm) * 264 + kt * 32 + lq * 8]);
    }
#pragma unroll
    for (int nt = 0; nt < 8; ++nt)
#pragma unroll
      for (int rt = 0; rt < 4; ++rt) {
        acc[nt][rt] = MFMA16(Ah[rt], asv(Bh[nt]), acc[nt][rt]);
        acc[nt][rt] = MFMA16(Ah[rt], asv(Bl[nt]), acc[nt][rt]);
        acc[nt][rt] = MFMA16(Al[rt], asv(Bh[nt]), acc[nt][rt]);
      }
  }
#pragma unroll
  for (int nt = 0; nt < 8; ++nt)
#pragma unroll
    for (int rt = 0; rt < 4; ++rt)
#pragma unroll
      for (int r = 0; r < 4; ++r) {
        size_t row = row0 + rt * 16 + lq * 4 + r;
        out[row * 1024 + (w * 8 + nt) * 16 + lm] = f2bu(acc[nt][rt][r]);
      }
}

// ---- phase 2: MFMA scan, M=1, LDS-traffic-minimized ----
// r10 diagnosis: step was LDS-pipe-bound (256 KB/step: i-gate 128 + full-wave
// obA/obW reads 128). For M=1 only A-row 0 is nonzero -> only lanes lm==0
// carry data: EXEC-MASK the obA/obW ds_reads (128 KB -> 8 KB/step). X store
// moved after the barrier so its ack drains a full step later.
#define LDH 264
#define SCAN_LDS (131072 + 2 * 16 * LDH * 2)

__global__ __launch_bounds__(512, 2) void scan3(
    const unsigned short* __restrict__ fiou, const unsigned short* __restrict__ wiouB,
    const unsigned short* __restrict__ wfB, const unsigned* __restrict__ ndg,
    float* __restrict__ X, float* __restrict__ gcs) {
  unsigned short* i_lds = (unsigned short*)smem;            // i-gate frags (128 KB)
  unsigned short* h_lds = (unsigned short*)(smem + 131072); // 16 x LDH
  unsigned short* o_lds = h_lds + 16 * LDH;                 // 16 x LDH
  __shared__ int okf;

  const int tid = threadIdx.x;
  const int w = tid >> 6, l = tid & 63;
  const int lm = l & 15, lq = l >> 4;
  const int b = blockIdx.x;          // one batch per block
  const int jj = 32 * w + lm;
  const int nt0 = 2 * w;
  const bool act = (lq == 0);        // lanes owning C row 0
  const bool arow = (lm == 0);       // lanes carrying A row 0

  if (tid == 0) okf = 1;
  const uint4* wp  = (const uint4*)wiouB;
  const uint4* wf4 = (const uint4*)wfB;
  {
    uint4* d = (uint4*)i_lds;
    for (int i = tid; i < 8192; i += 512) d[i] = wp[i];
  }
  for (int i = tid; i < 2 * 16 * LDH; i += 512) h_lds[i] = 0;
  uint4 wor[2][8], wur[2][8], wfr[2][8];
#pragma unroll
  for (int ts = 0; ts < 2; ++ts)
#pragma unroll
    for (int kt = 0; kt < 8; ++kt) {
      wor[ts][kt] = wp[((16 + (nt0 + ts)) * 8 + kt) * 64 + l];
      wur[ts][kt] = wp[((32 + (nt0 + ts)) * 8 + kt) * 64 + l];
      wfr[ts][kt] = wf4[((nt0 + ts) * 8 + kt) * 64 + l];
    }
  const unsigned* ndb = ndg + (b >> 4) * 4096 + (b & 15);  // stride 16 per t
  __syncthreads();

  if (tid < 256) {
    unsigned exp_ = (tid < 255)
        ? ((unsigned)tid | ((unsigned)(tid + 1) << 8) | 0x30000u)
        : (255u | 0x10000u);
    if (ndb[tid * 16] != exp_) atomicAnd(&okf, 0);
  }
  __syncthreads();

  const uint4* il4 = (const uint4*)i_lds;
  const f32x4 z4 = {0.f, 0.f, 0.f, 0.f};
  const size_t fb = ((size_t)b) << 18;  // fiou elems: b*256*1024
  const size_t xb = ((size_t)b) << 16;  // X/gcs elems: b*256*256

  if (okf != 0) {
    // ---------------- FAST PATH (chain, M=1) ----------------
    unsigned short* obA = h_lds;  // row 0 only used (elems [0,256))
    unsigned short* obW = o_lds;
    float gc_[2] = {0.f, 0.f};
    unsigned short rxi[2], rxo[2], rxu[2], rxf[2];
    if (act) {
#pragma unroll
      for (int ts = 0; ts < 2; ++ts) {
        int j = jj + ts * 16;
        rxi[ts] = fiou[fb + 256 + j];
        rxo[ts] = fiou[fb + 512 + j];
        rxu[ts] = fiou[fb + 768 + j];
        rxf[ts] = fiou[fb + 1024 + j];
      }
    }

    for (int t = 0; t < Nn; ++t) {
      // 1) iou MFMA; A-reads exec-masked to lanes lm==0 (rows 1-15 zero)
      f32x4 aI[2] = {z4, z4}, aO[2] = {z4, z4}, aU[2] = {z4, z4};
#pragma unroll
      for (int kt = 0; kt < 8; ++kt) {
        uint4 av = {0u, 0u, 0u, 0u};
        if (arow) av = *(const uint4*)&obA[kt * 32 + lq * 8];
        s16x8 a = asv(av);
#pragma unroll
        for (int ts = 0; ts < 2; ++ts) {
          aI[ts] = MFMA16(a, asv(il4[((nt0 + ts) * 8 + kt) * 64 + l]), aI[ts]);
          aO[ts] = MFMA16(a, asv(wor[ts][kt]), aO[ts]);
          aU[ts] = MFMA16(a, asv(wur[ts][kt]), aU[ts]);
        }
      }

      // 2) gating; obW row-0 write only
      float mem_[2], out_[2];
      if (act) {
#pragma unroll
        for (int ts = 0; ts < 2; ++ts) {
          float I  = aI[ts][0] + bu2f(rxi[ts]);
          float O  = aO[ts][0] + bu2f(rxo[ts]);
          float Uv = aU[ts][0] + bu2f(rxu[ts]);
          float memv = sigf(I) * tanh_(Uv) + gc_[ts];
          float outv = sigf(O) * tanh_(memv);
          mem_[ts] = memv;
          out_[ts] = outv;
          obW[jj + ts * 16] = f2bu(outv);
        }
      }
      __syncthreads();  // obW (= out_t) ready

      // 3) hs store AFTER the barrier (drains at next step's barrier)
      //    + prefetch t+1 iou gates (full step of cover)
      const int tgtN = (t < Nn - 1) ? t + 1 : t;
      if (act) {
#pragma unroll
        for (int ts = 0; ts < 2; ++ts)
          X[xb + (size_t)t * 256 + jj + ts * 16] = out_[ts];
        size_t fr = fb + (size_t)tgtN * 1024;
#pragma unroll
        for (int ts = 0; ts < 2; ++ts) {
          int j = jj + ts * 16;
          rxi[ts] = fiou[fr + 256 + j];
          rxo[ts] = fiou[fr + 512 + j];
          rxu[ts] = fiou[fr + 768 + j];
        }
      }

      // 4) f MFMA; masked A-reads from obW
      f32x4 aF[2] = {z4, z4};
#pragma unroll
      for (int kt = 0; kt < 8; ++kt) {
        uint4 av = {0u, 0u, 0u, 0u};
        if (arow) av = *(const uint4*)&obW[kt * 32 + lq * 8];
        s16x8 a = asv(av);
#pragma unroll
        for (int ts = 0; ts < 2; ++ts)
          aF[ts] = MFMA16(a, asv(wfr[ts][kt]), aF[ts]);
      }

      // 5) carry update + rxf prefetch for t+1
      if (act) {
#pragma unroll
        for (int ts = 0; ts < 2; ++ts) {
          float AF = aF[ts][0] + bu2f(rxf[ts]);
          gc_[ts] = sigf(AF) * mem_[ts];
        }
        int parN = (tgtN < 255) ? tgtN + 1 : 0;
        size_t fp = fb + (size_t)parN * 1024;
#pragma unroll
        for (int ts = 0; ts < 2; ++ts)
          rxf[ts] = fiou[fp + jj + ts * 16];
      }

      unsigned short* tmp = obA; obA = obW; obW = tmp;
    }
  } else {
    // ---------------- SLOW PATH (general tree, M=1; as r10) ----------------
    for (int t = 0; t < Nn; ++t) {
      unsigned nd_ = ndb[t * 16];
      int tgt = nd_ & 255, par = (nd_ >> 8) & 255;

      if (tid < 256)
        h_lds[tid] = f2bu(X[xb + (size_t)tgt * 256 + tid]);

      unsigned short rxi[2], rxo[2], rxu[2], rxf[2];
      float rgc[2], xold[2], gold[2];
      if (act) {
        size_t ft = fb + (size_t)tgt * 1024;
        size_t fp = fb + (size_t)par * 1024;
#pragma unroll
        for (int ts = 0; ts < 2; ++ts) {
          int j = jj + ts * 16;
          rxi[ts] = fiou[ft + 256 + j];
          rxo[ts] = fiou[ft + 512 + j];
          rxu[ts] = fiou[ft + 768 + j];
          rxf[ts] = fiou[fp + j];
          rgc[ts]  = gcs[xb + (size_t)tgt * 256 + j];
          xold[ts] = X[xb + (size_t)par * 256 + j];
          gold[ts] = gcs[xb + (size_t)par * 256 + j];
        }
      }
      __syncthreads();

      f32x4 aI[2] = {z4, z4}, aO[2] = {z4, z4}, aU[2] = {z4, z4};
#pragma unroll
      for (int kt = 0; kt < 8; ++kt) {
        uint4 av = *(const uint4*)&h_lds[lm * LDH + kt * 32 + lq * 8];
        s16x8 a = asv(av);
#pragma unroll
        for (int ts = 0; ts < 2; ++ts) {
          aI[ts] = MFMA16(a, asv(il4[((nt0 + ts) * 8 + kt) * 64 + l]), aI[ts]);
          aO[ts] = MFMA16(a, asv(wor[ts][kt]), aO[ts]);
          aU[ts] = MFMA16(a, asv(wur[ts][kt]), aU[ts]);
        }
      }

      float mem_[2], out_[2];
      if (act) {
#pragma unroll
        for (int ts = 0; ts < 2; ++ts) {
          float I  = aI[ts][0] + bu2f(rxi[ts]);
          float O  = aO[ts][0] + bu2f(rxo[ts]);
          float Uv = aU[ts][0] + bu2f(rxu[ts]);
          float memv = sigf(I) * tanh_(Uv) + rgc[ts];
          float outv = sigf(O) * tanh_(memv);
          mem_[ts] = memv;
          out_[ts] = outv;
          o_lds[jj + ts * 16] = f2bu(outv);
        }
      }
      __syncthreads();

      f32x4 aF[2] = {z4, z4};
#pragma unroll
      for (int kt = 0; kt < 8; ++kt) {
        uint4 av = *(const uint4*)&o_lds[lm * LDH + kt * 32 + lq * 8];
        s16x8 a = asv(av);
#pragma unroll
        for (int ts = 0; ts < 2; ++ts)
          aF[ts] = MFMA16(a, asv(wfr[ts][kt]), aF[ts]);
      }

      if (act) {
#pragma unroll
        for (int ts = 0; ts < 2; ++ts) {
          int j = jj + ts * 16;
          float AF = aF[ts][0] + bu2f(rxf[ts]);
          float gated = sigf(AF) * mem_[ts];
          if (nd_ & 0x10000u) X[xb + (size_t)tgt * 256 + j] = out_[ts];
          if (nd_ & 0x20000u) {
            X[xb + (size_t)par * 256 + j] = xold[ts] + out_[ts];
            gcs[xb + (size_t)par * 256 + j] = gold[ts] + gated;
          }
        }
      }
      __syncthreads();
    }
  }
}

extern "C" void kernel_launch(void* const* d_in, const int* in_sizes, int n_in,
                              void* d_out, int out_size, void* d_ws, size_t ws_size,
                              hipStream_t stream) {
  const float* inputs = (const float*)d_in[0];
  const int* parents  = (const int*)d_in[1];
  const int* post     = (const int*)d_in[2];
  const float* xw     = (const float*)d_in[3];
  const float* hf     = (const float*)d_in[4];
  const float* hiou   = (const float*)d_in[5];
  const float* bias   = (const float*)d_in[6];
  float* X = (float*)d_out;  // csh-then-hs buffer (fast path: hs only)

  // ws layout:
  //   [0, 128 MiB)   fiou_xb bf16
  //   +134217728     gcs fp32      64 MiB
  //   +201326592     wiouB bf16    384 KiB
  //   +201719808     wfB bf16      128 KiB
  //   +201850880     ndg u32       256 KiB   (end 202113024)
  //   +202113024     xwHi bf16     512 KiB   (optional, ws permitting)
  //   +202637312     xwLo bf16     512 KiB
  char* ws = (char*)d_ws;
  bf16* fiou     = (bf16*)ws;
  float* gcs     = (float*)(ws + (size_t)134217728);
  bf16* wiouB    = (bf16*)(ws + (size_t)201326592);
  bf16* wfB      = (bf16*)(ws + (size_t)201719808);
  unsigned* ndg  = (unsigned*)(ws + (size_t)201850880);
  bf16* xwHi     = (bf16*)(ws + (size_t)202113024);
  bf16* xwLo     = (bf16*)(ws + (size_t)202637312);
  const bool big_ws = ws_size >= (size_t)202113024 + 2 * 524288;

  hipMemsetAsync(X, 0, (size_t)Bq * Nn * Uu * sizeof(float), stream);
  hipMemsetAsync(gcs, 0, (size_t)Bq * Nn * Uu * sizeof(float), stream);

  hipFuncSetAttribute(reinterpret_cast<const void*>(scan3),
                      hipFuncAttributeMaxDynamicSharedMemorySize, SCAN_LDS);

  prep_weights<<<1024, 256, 0, stream>>>(hiou, hf, wiouB, wfB);
  prep_nd<<<256, 256, 0, stream>>>(parents, post, ndg);
  if (big_ws) {
    hipFuncSetAttribute(reinterpret_cast<const void*>(xproj2),
                        hipFuncAttributeMaxDynamicSharedMemorySize, XP_LDS);
    prep_xw<<<1024, 256, 0, stream>>>(xw, xwHi, xwLo);
    xproj2<<<(Bq * Nn) / 64, 512, XP_LDS, stream>>>(
        inputs, (const unsigned short*)xwHi, (const unsigned short*)xwLo,
        bias, (unsigned short*)fiou);
  } else {
    xproj<<<(Bq * Nn) / 16, 256, 0, stream>>>(inputs, xw, bias, (bf16*)fiou);
  }
  scan3<<<256, 512, SCAN_LDS, stream>>>((const unsigned short*)fiou,
                                        (const unsigned short*)wiouB,
                                        (const unsigned short*)wfB,
                                        ndg, X, gcs);
}

// Round 14
// 1561.611 us; speedup vs baseline: 2.1610x; 1.0530x over previous
//
#include <hip/hip_runtime.h>
#include <hip/hip_bf16.h>

#define Bq 256
#define Nn 256
#define Dd 256
#define Uu 256

using bf16 = __hip_bfloat16;

typedef __attribute__((ext_vector_type(8))) short s16x8;
typedef __attribute__((ext_vector_type(4))) float f32x4;

__device__ __forceinline__ float bu2f(unsigned short u) {
  return __uint_as_float(((unsigned)u) << 16);
}
__device__ __forceinline__ unsigned short f2bu(float f) {
  union { bf16 h; unsigned short u; } c; c.h = __float2bfloat16(f); return c.u;
}
__device__ __forceinline__ float sigf(float x) { return 1.0f / (1.0f + __expf(-x)); }
__device__ __forceinline__ float tanh_(float x) { return 2.0f / (1.0f + __expf(-2.0f * x)) - 1.0f; }
__device__ __forceinline__ s16x8 asv(uint4 x) {
  union { uint4 u; s16x8 v; } c; c.u = x; return c.v;
}
#define MFMA16(a, b, c) __builtin_amdgcn_mfma_f32_16x16x32_bf16(a, b, c, 0, 0, 0)

// ---- weight prep: build MFMA B-fragments (bf16) for wiou and wf ----
__global__ __launch_bounds__(256) void prep_weights(
    const float* __restrict__ hiou, const float* __restrict__ hf,
    bf16* __restrict__ wiouB, bf16* __restrict__ wfB) {
  int idx = blockIdx.x * 256 + threadIdx.x;  // 262144 total
  int e = idx & 7, l = (idx >> 3) & 63, kt = (idx >> 9) & 7;
  int k = kt * 32 + (l >> 4) * 8 + e;
  if (idx < 196608) {
    int nt = (idx >> 12) & 15, g = idx >> 16;
    wiouB[idx] = __float2bfloat16(hiou[k * 768 + g * 256 + nt * 16 + (l & 15)]);
  } else {
    int t = idx - 196608;
    int nt = (t >> 12) & 15;
    wfB[t] = __float2bfloat16(hf[k * 256 + nt * 16 + (l & 15)]);
  }
}

// ---- xw B-fragments, hi/lo split (for MFMA xproj) ----
__global__ __launch_bounds__(256) void prep_xw(
    const float* __restrict__ xw, bf16* __restrict__ xwHi, bf16* __restrict__ xwLo) {
  int idx = blockIdx.x * 256 + threadIdx.x;  // 262144
  int e = idx & 7, l = (idx >> 3) & 63, kt = (idx >> 9) & 7, nt = idx >> 12;
  int k = kt * 32 + (l >> 4) * 8 + e;
  float v = xw[k * 1024 + nt * 16 + (l & 15)];
  bf16 h = __float2bfloat16(v);
  xwHi[idx] = h;
  xwLo[idx] = __float2bfloat16(v - (float)h);
}

// ---- node-info table ----
__global__ __launch_bounds__(256) void prep_nd(
    const int* __restrict__ parents, const int* __restrict__ post,
    unsigned* __restrict__ ndg) {
  int idx = blockIdx.x * 256 + threadIdx.x;  // 65536
  int b = idx >> 8, t = idx & 255;
  int po = post[b * 256 + t];
  int om = po >= 0;
  int tgt = om ? po : 0;
  int praw = parents[b * 256 + tgt];
  int pm = (praw >= 0) && om;
  int par = praw >= 0 ? praw : 0;
  unsigned word = (unsigned)(tgt & 255) | ((unsigned)(par & 255) << 8) |
                  ((unsigned)om << 16) | ((unsigned)pm << 17);
  ndg[(b >> 4) * 4096 + t * 16 + (b & 15)] = word;
}

extern __shared__ char smem[];

// ---- phase 1 fallback: fp32 VALU xproj (used if ws too small) ----
__global__ __launch_bounds__(256) void xproj(
    const float* __restrict__ x, const float* __restrict__ w,
    const float* __restrict__ bias, bf16* __restrict__ out) {
  __shared__ float xs[Dd][16];
  const int tid = threadIdx.x;
  const int row0 = blockIdx.x * 16;
  for (int i = 0; i < 16; ++i) {
    int idx = i * 256 + tid;
    int r = idx >> 8, k = idx & 255;
    xs[k][r] = x[(size_t)(row0 + r) * Dd + k];
  }
  __syncthreads();
  const int c0 = tid * 4;
  float4 bv = *(const float4*)(bias + c0);
  float acc[16][4];
#pragma unroll
  for (int r = 0; r < 16; ++r) {
    acc[r][0] = bv.x; acc[r][1] = bv.y; acc[r][2] = bv.z; acc[r][3] = bv.w;
  }
  for (int k = 0; k < Dd; ++k) {
    float4 wv = *(const float4*)(w + (size_t)k * 1024 + c0);
    const float4* xr = (const float4*)xs[k];
    float4 x0 = xr[0], x1 = xr[1], x2 = xr[2], x3 = xr[3];
    float xv[16] = {x0.x, x0.y, x0.z, x0.w, x1.x, x1.y, x1.z, x1.w,
                    x2.x, x2.y, x2.z, x2.w, x3.x, x3.y, x3.z, x3.w};
#pragma unroll
    for (int r = 0; r < 16; ++r) {
      acc[r][0] += xv[r] * wv.x;
      acc[r][1] += xv[r] * wv.y;
      acc[r][2] += xv[r] * wv.z;
      acc[r][3] += xv[r] * wv.w;
    }
  }
#pragma unroll
  for (int r = 0; r < 16; ++r) {
    union { ushort4 u4; bf16 b[4]; } pk;
    pk.b[0] = __float2bfloat16(acc[r][0]);
    pk.b[1] = __float2bfloat16(acc[r][1]);
    pk.b[2] = __float2bfloat16(acc[r][2]);
    pk.b[3] = __float2bfloat16(acc[r][3]);
    *(ushort4*)(&out[(size_t)(row0 + r) * 1024 + c0]) = pk.u4;
  }
}

// ---- phase 1: MFMA xproj with hi/lo split (as r13, measured) ----
#define XP_LDS (2 * 64 * 264 * 2)
__global__ __launch_bounds__(512, 2) void xproj2(
    const float* __restrict__ x, const unsigned short* __restrict__ xwHi,
    const unsigned short* __restrict__ xwLo, const float* __restrict__ bias,
    unsigned short* __restrict__ out) {
  unsigned short* a_hi = (unsigned short*)smem;             // [64][264]
  unsigned short* a_lo = a_hi + 64 * 264;
  const int tid = threadIdx.x;
  const int w = tid >> 6, l = tid & 63;
  const int lm = l & 15, lq = l >> 4;
  const size_t row0 = (size_t)blockIdx.x * 64;

  {
    int r = tid >> 3, c0 = (tid & 7) * 32;
    const float* src = x + (row0 + r) * 256 + c0;
#pragma unroll
    for (int c = 0; c < 32; c += 4) {
      float4 v = *(const float4*)(src + c);
      unsigned short h0 = f2bu(v.x), h1 = f2bu(v.y), h2 = f2bu(v.z), h3 = f2bu(v.w);
      ushort4 hv = {h0, h1, h2, h3};
      ushort4 lv = {f2bu(v.x - bu2f(h0)), f2bu(v.y - bu2f(h1)),
                    f2bu(v.z - bu2f(h2)), f2bu(v.w - bu2f(h3))};
      *(ushort4*)&a_hi[r * 264 + c0 + c] = hv;
      *(ushort4*)&a_lo[r * 264 + c0 + c] = lv;
    }
  }
  __syncthreads();

  const uint4* bh = (const uint4*)xwHi;
  const uint4* bl = (const uint4*)xwLo;
  f32x4 acc[8][4];
#pragma unroll
  for (int nt = 0; nt < 8; ++nt) {
    float b = bias[(w * 8 + nt) * 16 + lm];
#pragma unroll
    for (int rt = 0; rt < 4; ++rt) acc[nt][rt] = {b, b, b, b};
  }
  for (int kt = 0; kt < 8; ++kt) {
    uint4 Bh[8], Bl[8];
#pragma unroll
    for (int nt = 0; nt < 8; ++nt) {
      int f = ((w * 8 + nt) * 8 + kt) * 64 + l;
      Bh[nt] = bh[f];
      Bl[nt] = bl[f];
    }
    s16x8 Ah[4], Al[4];
#pragma unroll
    for (int rt = 0; rt < 4; ++rt) {
      Ah[rt] = asv(*(const uint4*)&a_hi[(rt * 16 + lm) * 264 + kt * 32 + lq * 8]);
      Al[rt] = asv(*(const uint4*)&a_lo[(rt * 16 + lm) * 264 + kt * 32 + lq * 8]);
    }
#pragma unroll
    for (int nt = 0; nt < 8; ++nt)
#pragma unroll
      for (int rt = 0; rt < 4; ++rt) {
        acc[nt][rt] = MFMA16(Ah[rt], asv(Bh[nt]), acc[nt][rt]);
        acc[nt][rt] = MFMA16(Ah[rt], asv(Bl[nt]), acc[nt][rt]);
        acc[nt][rt] = MFMA16(Al[rt], asv(Bh[nt]), acc[nt][rt]);
      }
  }
#pragma unroll
  for (int nt = 0; nt < 8; ++nt)
#pragma unroll
    for (int rt = 0; rt < 4; ++rt)
#pragma unroll
      for (int r = 0; r < 4; ++r) {
        size_t row = row0 + rt * 16 + lq * 4 + r;
        out[row * 1024 + (w * 8 + nt) * 16 + lm] = f2bu(acc[nt][rt][r]);
      }
}

// ---- phase 2: MFMA scan, M=1, FUSED single MFMA cluster per step ----
// r13 diagnosis: step ~4130cy at 740MHz eff.; MFMA 640cy + LDS 1000cy +
// VALU 785cy all overlappable => ~2500cy is stall from TWO separate MFMA
// phases (each with its own lgkm ramp) + double masked A-reads + the
// f->carry->iou serialization. Fusion: f-gemv(t) and iou-gemv(t+1) BOTH
// read out_t => one fused 64-MFMA cluster per step, 8 masked A-reads
// (was 16), one barrier. Ping-pong keeps write(t+1)/read(t) barrier-safe.
#define LDH 264
#define SCAN_LDS (131072 + 2 * 16 * LDH * 2)

__global__ __launch_bounds__(512, 2) void scan3(
    const unsigned short* __restrict__ fiou, const unsigned short* __restrict__ wiouB,
    const unsigned short* __restrict__ wfB, const unsigned* __restrict__ ndg,
    float* __restrict__ X, float* __restrict__ gcs) {
  unsigned short* i_lds = (unsigned short*)smem;            // i-gate frags (128 KB)
  unsigned short* h_lds = (unsigned short*)(smem + 131072); // 16 x LDH
  unsigned short* o_lds = h_lds + 16 * LDH;                 // 16 x LDH
  __shared__ int okf;

  const int tid = threadIdx.x;
  const int w = tid >> 6, l = tid & 63;
  const int lm = l & 15, lq = l >> 4;
  const int b = blockIdx.x;          // one batch per block
  const int jj = 32 * w + lm;
  const int nt0 = 2 * w;
  const bool act = (lq == 0);        // lanes owning C row 0
  const bool arow = (lm == 0);       // lanes carrying A row 0

  if (tid == 0) okf = 1;
  const uint4* wp  = (const uint4*)wiouB;
  const uint4* wf4 = (const uint4*)wfB;
  {
    uint4* d = (uint4*)i_lds;
    for (int i = tid; i < 8192; i += 512) d[i] = wp[i];
  }
  for (int i = tid; i < 2 * 16 * LDH; i += 512) h_lds[i] = 0;
  uint4 wor[2][8], wur[2][8], wfr[2][8];
#pragma unroll
  for (int ts = 0; ts < 2; ++ts)
#pragma unroll
    for (int kt = 0; kt < 8; ++kt) {
      wor[ts][kt] = wp[((16 + (nt0 + ts)) * 8 + kt) * 64 + l];
      wur[ts][kt] = wp[((32 + (nt0 + ts)) * 8 + kt) * 64 + l];
      wfr[ts][kt] = wf4[((nt0 + ts) * 8 + kt) * 64 + l];
    }
  const unsigned* ndb = ndg + (b >> 4) * 4096 + (b & 15);  // stride 16 per t
  __syncthreads();

  if (tid < 256) {
    unsigned exp_ = (tid < 255)
        ? ((unsigned)tid | ((unsigned)(tid + 1) << 8) | 0x30000u)
        : (255u | 0x10000u);
    if (ndb[tid * 16] != exp_) atomicAnd(&okf, 0);
  }
  __syncthreads();

  const uint4* il4 = (const uint4*)i_lds;
  const f32x4 z4 = {0.f, 0.f, 0.f, 0.f};
  const size_t fb = ((size_t)b) << 18;  // fiou elems: b*256*1024
  const size_t xb = ((size_t)b) << 16;  // X/gcs elems: b*256*256

  if (okf != 0) {
    // ---------------- FAST PATH (chain, M=1, fused cluster) ----------------
    unsigned short* bufA = h_lds;  // gating(t) writes out_t here
    unsigned short* bufB = o_lds;
    float gc_[2] = {0.f, 0.f};
    // acc_iou for t=0: h_0 = 0 => exact zeros
    f32x4 accI[2] = {z4, z4}, accO[2] = {z4, z4}, accU[2] = {z4, z4};
    unsigned short rxi[2], rxo[2], rxu[2], rxf[2];
    if (act) {
#pragma unroll
      for (int ts = 0; ts < 2; ++ts) {
        int j = jj + ts * 16;
        rxi[ts] = fiou[fb + 256 + j];       // row 0 (tgt=0)
        rxo[ts] = fiou[fb + 512 + j];
        rxu[ts] = fiou[fb + 768 + j];
        rxf[ts] = fiou[fb + 1024 + j];      // row 1 (par=1), f slice
      }
    }

    for (int t = 0; t < Nn; ++t) {
      // 1) gating(t): uses acc_iou(t) (from prev cluster) + gc_{t-1}
      float mem_[2], out_[2];
      if (act) {
#pragma unroll
        for (int ts = 0; ts < 2; ++ts) {
          float I  = accI[ts][0] + bu2f(rxi[ts]);
          float O  = accO[ts][0] + bu2f(rxo[ts]);
          float Uv = accU[ts][0] + bu2f(rxu[ts]);
          float memv = sigf(I) * tanh_(Uv) + gc_[ts];
          float outv = sigf(O) * tanh_(memv);
          mem_[ts] = memv;
          out_[ts] = outv;
          bufA[jj + ts * 16] = f2bu(outv);
        }
      }
      __syncthreads();  // out_t visible in bufA

      // 2) hs store + prefetch rx(t+1) (full interval of cover)
      const int tgtN = (t < Nn - 1) ? t + 1 : t;
      if (act) {
#pragma unroll
        for (int ts = 0; ts < 2; ++ts)
          X[xb + (size_t)t * 256 + jj + ts * 16] = out_[ts];
        size_t fr = fb + (size_t)tgtN * 1024;
#pragma unroll
        for (int ts = 0; ts < 2; ++ts) {
          int j = jj + ts * 16;
          rxi[ts] = fiou[fr + 256 + j];
          rxo[ts] = fiou[fr + 512 + j];
          rxu[ts] = fiou[fr + 768 + j];
        }
      }

      // 3) FUSED cluster: one masked read of out_t per kt feeds f(t) AND
      //    iou(t+1). 8 independent accumulator chains, 64 MFMAs.
      f32x4 aF[2] = {z4, z4};
#pragma unroll
      for (int ts = 0; ts < 2; ++ts) { accI[ts] = z4; accO[ts] = z4; accU[ts] = z4; }
#pragma unroll
      for (int kt = 0; kt < 8; ++kt) {
        uint4 av = {0u, 0u, 0u, 0u};
        if (arow) av = *(const uint4*)&bufA[kt * 32 + lq * 8];
        s16x8 a = asv(av);
#pragma unroll
        for (int ts = 0; ts < 2; ++ts) {
          aF[ts]   = MFMA16(a, asv(wfr[ts][kt]), aF[ts]);
          accI[ts] = MFMA16(a, asv(il4[((nt0 + ts) * 8 + kt) * 64 + l]), accI[ts]);
          accO[ts] = MFMA16(a, asv(wor[ts][kt]), accO[ts]);
          accU[ts] = MFMA16(a, asv(wur[ts][kt]), accU[ts]);
        }
      }

      // 4) carry: gc_t = sig(aF + xf[par_t]) * mem_t ; prefetch rxf(t+1)
      if (act) {
#pragma unroll
        for (int ts = 0; ts < 2; ++ts) {
          float AF = aF[ts][0] + bu2f(rxf[ts]);
          gc_[ts] = sigf(AF) * mem_[ts];
        }
        int parN = (tgtN < 255) ? tgtN + 1 : 0;
        size_t fp = fb + (size_t)parN * 1024;
#pragma unroll
        for (int ts = 0; ts < 2; ++ts)
          rxf[ts] = fiou[fp + jj + ts * 16];
      }

      // ping-pong: next gating writes the other buffer (reads of bufA are
      // all pre-barrier(t+1), so bufA is reusable at t+2)
      unsigned short* tmp = bufA; bufA = bufB; bufB = tmp;
    }
  } else {
    // ---------------- SLOW PATH (general tree, M=1; as r10/r13) ----------
    for (int t = 0; t < Nn; ++t) {
      unsigned nd_ = ndb[t * 16];
      int tgt = nd_ & 255, par = (nd_ >> 8) & 255;

      if (tid < 256)
        h_lds[tid] = f2bu(X[xb + (size_t)tgt * 256 + tid]);

      unsigned short rxi[2], rxo[2], rxu[2], rxf[2];
      float rgc[2], xold[2], gold[2];
      if (act) {
        size_t ft = fb + (size_t)tgt * 1024;
        size_t fp = fb + (size_t)par * 1024;
#pragma unroll
        for (int ts = 0; ts < 2; ++ts) {
          int j = jj + ts * 16;
          rxi[ts] = fiou[ft + 256 + j];
          rxo[ts] = fiou[ft + 512 + j];
          rxu[ts] = fiou[ft + 768 + j];
          rxf[ts] = fiou[fp + j];
          rgc[ts]  = gcs[xb + (size_t)tgt * 256 + j];
          xold[ts] = X[xb + (size_t)par * 256 + j];
          gold[ts] = gcs[xb + (size_t)par * 256 + j];
        }
      }
      __syncthreads();

      f32x4 aI[2] = {z4, z4}, aO[2] = {z4, z4}, aU[2] = {z4, z4};
#pragma unroll
      for (int kt = 0; kt < 8; ++kt) {
        uint4 av = *(const uint4*)&h_lds[lm * LDH + kt * 32 + lq * 8];
        s16x8 a = asv(av);
#pragma unroll
        for (int ts = 0; ts < 2; ++ts) {
          aI[ts] = MFMA16(a, asv(il4[((nt0 + ts) * 8 + kt) * 64 + l]), aI[ts]);
          aO[ts] = MFMA16(a, asv(wor[ts][kt]), aO[ts]);
          aU[ts] = MFMA16(a, asv(wur[ts][kt]), aU[ts]);
        }
      }

      float mem_[2], out_[2];
      if (act) {
#pragma unroll
        for (int ts = 0; ts < 2; ++ts) {
          float I  = aI[ts][0] + bu2f(rxi[ts]);
          float O  = aO[ts][0] + bu2f(rxo[ts]);
          float Uv = aU[ts][0] + bu2f(rxu[ts]);
          float memv = sigf(I) * tanh_(Uv) + rgc[ts];
          float outv = sigf(O) * tanh_(memv);
          mem_[ts] = memv;
          out_[ts] = outv;
          o_lds[jj + ts * 16] = f2bu(outv);
        }
      }
      __syncthreads();

      f32x4 aF[2] = {z4, z4};
#pragma unroll
      for (int kt = 0; kt < 8; ++kt) {
        uint4 av = *(const uint4*)&o_lds[lm * LDH + kt * 32 + lq * 8];
        s16x8 a = asv(av);
#pragma unroll
        for (int ts = 0; ts < 2; ++ts)
          aF[ts] = MFMA16(a, asv(wfr[ts][kt]), aF[ts]);
      }

      if (act) {
#pragma unroll
        for (int ts = 0; ts < 2; ++ts) {
          int j = jj + ts * 16;
          float AF = aF[ts][0] + bu2f(rxf[ts]);
          float gated = sigf(AF) * mem_[ts];
          if (nd_ & 0x10000u) X[xb + (size_t)tgt * 256 + j] = out_[ts];
          if (nd_ & 0x20000u) {
            X[xb + (size_t)par * 256 + j] = xold[ts] + out_[ts];
            gcs[xb + (size_t)par * 256 + j] = gold[ts] + gated;
          }
        }
      }
      __syncthreads();
    }
  }
}

extern "C" void kernel_launch(void* const* d_in, const int* in_sizes, int n_in,
                              void* d_out, int out_size, void* d_ws, size_t ws_size,
                              hipStream_t stream) {
  const float* inputs = (const float*)d_in[0];
  const int* parents  = (const int*)d_in[1];
  const int* post     = (const int*)d_in[2];
  const float* xw     = (const float*)d_in[3];
  const float* hf     = (const float*)d_in[4];
  const float* hiou   = (const float*)d_in[5];
  const float* bias   = (const float*)d_in[6];
  float* X = (float*)d_out;  // csh-then-hs buffer (fast path: hs only)

  // ws layout:
  //   [0, 128 MiB)   fiou_xb bf16
  //   +134217728     gcs fp32      64 MiB
  //   +201326592     wiouB bf16    384 KiB
  //   +201719808     wfB bf16      128 KiB
  //   +201850880     ndg u32       256 KiB   (end 202113024)
  //   +202113024     xwHi bf16     512 KiB   (optional, ws permitting)
  //   +202637312     xwLo bf16     512 KiB
  char* ws = (char*)d_ws;
  bf16* fiou     = (bf16*)ws;
  float* gcs     = (float*)(ws + (size_t)134217728);
  bf16* wiouB    = (bf16*)(ws + (size_t)201326592);
  bf16* wfB      = (bf16*)(ws + (size_t)201719808);
  unsigned* ndg  = (unsigned*)(ws + (size_t)201850880);
  bf16* xwHi     = (bf16*)(ws + (size_t)202113024);
  bf16* xwLo     = (bf16*)(ws + (size_t)202637312);
  const bool big_ws = ws_size >= (size_t)202113024 + 2 * 524288;

  hipMemsetAsync(X, 0, (size_t)Bq * Nn * Uu * sizeof(float), stream);
  hipMemsetAsync(gcs, 0, (size_t)Bq * Nn * Uu * sizeof(float), stream);

  hipFuncSetAttribute(reinterpret_cast<const void*>(scan3),
                      hipFuncAttributeMaxDynamicSharedMemorySize, SCAN_LDS);

  prep_weights<<<1024, 256, 0, stream>>>(hiou, hf, wiouB, wfB);
  prep_nd<<<256, 256, 0, stream>>>(parents, post, ndg);
  if (big_ws) {
    hipFuncSetAttribute(reinterpret_cast<const void*>(xproj2),
                        hipFuncAttributeMaxDynamicSharedMemorySize, XP_LDS);
    prep_xw<<<1024, 256, 0, stream>>>(xw, xwHi, xwLo);
    xproj2<<<(Bq * Nn) / 64, 512, XP_LDS, stream>>>(
        inputs, (const unsigned short*)xwHi, (const unsigned short*)xwLo,
        bias, (unsigned short*)fiou);
  } else {
    xproj<<<(Bq * Nn) / 16, 256, 0, stream>>>(inputs, xw, bias, (bf16*)fiou);
  }
  scan3<<<256, 512, SCAN_LDS, stream>>>((const unsigned short*)fiou,
                                        (const unsigned short*)wiouB,
                                        (const unsigned short*)wfB,
                                        ndg, X, gcs);
}

// Round 17
// 1518.695 us; speedup vs baseline: 2.2221x; 1.0283x over previous
//
#include <hip/hip_runtime.h>
#include <hip/hip_bf16.h>

#define Bq 256
#define Nn 256
#define Dd 256
#define Uu 256

using bf16 = __hip_bfloat16;

typedef __attribute__((ext_vector_type(8))) short s16x8;
typedef __attribute__((ext_vector_type(4))) float f32x4;

__device__ __forceinline__ float bu2f(unsigned short u) {
  return __uint_as_float(((unsigned)u) << 16);
}
__device__ __forceinline__ unsigned short f2bu(float f) {
  union { bf16 h; unsigned short u; } c; c.h = __float2bfloat16(f); return c.u;
}
__device__ __forceinline__ float sigf(float x) { return 1.0f / (1.0f + __expf(-x)); }
__device__ __forceinline__ float tanh_(float x) { return 2.0f / (1.0f + __expf(-2.0f * x)) - 1.0f; }
__device__ __forceinline__ s16x8 asv(uint4 x) {
  union { uint4 u; s16x8 v; } c; c.u = x; return c.v;
}
#define MFMA16(a, b, c) __builtin_amdgcn_mfma_f32_16x16x32_bf16(a, b, c, 0, 0, 0)

// Fast-path barrier: drain LDS only (NOT vmcnt) so X stores and fiou
// prefetches stay in flight across steps. __syncthreads() would emit
// s_waitcnt vmcnt(0) and eat an HBM latency every step. Safe: LDS is the
// only cross-wave medium; in-flight VMEM is write-only X + private loads.
#define FAST_BAR() do {                                   \
    __builtin_amdgcn_sched_barrier(0);                    \
    asm volatile("s_waitcnt lgkmcnt(0)" ::: "memory");    \
    __builtin_amdgcn_s_barrier();                         \
    __builtin_amdgcn_sched_barrier(0);                    \
  } while (0)

// ---- weight prep: build MFMA B-fragments (bf16) for wiou and wf ----
__global__ __launch_bounds__(256) void prep_weights(
    const float* __restrict__ hiou, const float* __restrict__ hf,
    bf16* __restrict__ wiouB, bf16* __restrict__ wfB) {
  int idx = blockIdx.x * 256 + threadIdx.x;  // 262144 total
  int e = idx & 7, l = (idx >> 3) & 63, kt = (idx >> 9) & 7;
  int k = kt * 32 + (l >> 4) * 8 + e;
  if (idx < 196608) {
    int nt = (idx >> 12) & 15, g = idx >> 16;
    wiouB[idx] = __float2bfloat16(hiou[k * 768 + g * 256 + nt * 16 + (l & 15)]);
  } else {
    int t = idx - 196608;
    int nt = (t >> 12) & 15;
    wfB[t] = __float2bfloat16(hf[k * 256 + nt * 16 + (l & 15)]);
  }
}

// ---- xw B-fragments, hi/lo split (for MFMA xproj) ----
__global__ __launch_bounds__(256) void prep_xw(
    const float* __restrict__ xw, bf16* __restrict__ xwHi, bf16* __restrict__ xwLo) {
  int idx = blockIdx.x * 256 + threadIdx.x;  // 262144
  int e = idx & 7, l = (idx >> 3) & 63, kt = (idx >> 9) & 7, nt = idx >> 12;
  int k = kt * 32 + (l >> 4) * 8 + e;
  float v = xw[k * 1024 + nt * 16 + (l & 15)];
  bf16 h = __float2bfloat16(v);
  xwHi[idx] = h;
  xwLo[idx] = __float2bfloat16(v - (float)h);
}

// ---- node-info table ----
__global__ __launch_bounds__(256) void prep_nd(
    const int* __restrict__ parents, const int* __restrict__ post,
    unsigned* __restrict__ ndg) {
  int idx = blockIdx.x * 256 + threadIdx.x;  // 65536
  int b = idx >> 8, t = idx & 255;
  int po = post[b * 256 + t];
  int om = po >= 0;
  int tgt = om ? po : 0;
  int praw = parents[b * 256 + tgt];
  int pm = (praw >= 0) && om;
  int par = praw >= 0 ? praw : 0;
  unsigned word = (unsigned)(tgt & 255) | ((unsigned)(par & 255) << 8) |
                  ((unsigned)om << 16) | ((unsigned)pm << 17);
  ndg[(b >> 4) * 4096 + t * 16 + (b & 15)] = word;
}

extern __shared__ char smem[];

// ---- phase 1 fallback: fp32 VALU xproj (used if ws too small) ----
__global__ __launch_bounds__(256) void xproj(
    const float* __restrict__ x, const float* __restrict__ w,
    const float* __restrict__ bias, bf16* __restrict__ out) {
  __shared__ float xs[Dd][16];
  const int tid = threadIdx.x;
  const int row0 = blockIdx.x * 16;
  for (int i = 0; i < 16; ++i) {
    int idx = i * 256 + tid;
    int r = idx >> 8, k = idx & 255;
    xs[k][r] = x[(size_t)(row0 + r) * Dd + k];
  }
  __syncthreads();
  const int c0 = tid * 4;
  float4 bv = *(const float4*)(bias + c0);
  float acc[16][4];
#pragma unroll
  for (int r = 0; r < 16; ++r) {
    acc[r][0] = bv.x; acc[r][1] = bv.y; acc[r][2] = bv.z; acc[r][3] = bv.w;
  }
  for (int k = 0; k < Dd; ++k) {
    float4 wv = *(const float4*)(w + (size_t)k * 1024 + c0);
    const float4* xr = (const float4*)xs[k];
    float4 x0 = xr[0], x1 = xr[1], x2 = xr[2], x3 = xr[3];
    float xv[16] = {x0.x, x0.y, x0.z, x0.w, x1.x, x1.y, x1.z, x1.w,
                    x2.x, x2.y, x2.z, x2.w, x3.x, x3.y, x3.z, x3.w};
#pragma unroll
    for (int r = 0; r < 16; ++r) {
      acc[r][0] += xv[r] * wv.x;
      acc[r][1] += xv[r] * wv.y;
      acc[r][2] += xv[r] * wv.z;
      acc[r][3] += xv[r] * wv.w;
    }
  }
#pragma unroll
  for (int r = 0; r < 16; ++r) {
    union { ushort4 u4; bf16 b[4]; } pk;
    pk.b[0] = __float2bfloat16(acc[r][0]);
    pk.b[1] = __float2bfloat16(acc[r][1]);
    pk.b[2] = __float2bfloat16(acc[r][2]);
    pk.b[3] = __float2bfloat16(acc[r][3]);
    *(ushort4*)(&out[(size_t)(row0 + r) * 1024 + c0]) = pk.u4;
  }
}

// ---- phase 1: MFMA xproj with hi/lo split (as r13/r14, measured) ----
#define XP_LDS (2 * 64 * 264 * 2)
__global__ __launch_bounds__(512, 2) void xproj2(
    const float* __restrict__ x, const unsigned short* __restrict__ xwHi,
    const unsigned short* __restrict__ xwLo, const float* __restrict__ bias,
    unsigned short* __restrict__ out) {
  unsigned short* a_hi = (unsigned short*)smem;             // [64][264]
  unsigned short* a_lo = a_hi + 64 * 264;
  const int tid = threadIdx.x;
  const int w = tid >> 6, l = tid & 63;
  const int lm = l & 15, lq = l >> 4;
  const size_t row0 = (size_t)blockIdx.x * 64;

  {
    int r = tid >> 3, c0 = (tid & 7) * 32;
    const float* src = x + (row0 + r) * 256 + c0;
#pragma unroll
    for (int c = 0; c < 32; c += 4) {
      float4 v = *(const float4*)(src + c);
      unsigned short h0 = f2bu(v.x), h1 = f2bu(v.y), h2 = f2bu(v.z), h3 = f2bu(v.w);
      ushort4 hv = {h0, h1, h2, h3};
      ushort4 lv = {f2bu(v.x - bu2f(h0)), f2bu(v.y - bu2f(h1)),
                    f2bu(v.z - bu2f(h2)), f2bu(v.w - bu2f(h3))};
      *(ushort4*)&a_hi[r * 264 + c0 + c] = hv;
      *(ushort4*)&a_lo[r * 264 + c0 + c] = lv;
    }
  }
  __syncthreads();

  const uint4* bh = (const uint4*)xwHi;
  const uint4* bl = (const uint4*)xwLo;
  f32x4 acc[8][4];
#pragma unroll
  for (int nt = 0; nt < 8; ++nt) {
    float b = bias[(w * 8 + nt) * 16 + lm];
#pragma unroll
    for (int rt = 0; rt < 4; ++rt) acc[nt][rt] = {b, b, b, b};
  }
  for (int kt = 0; kt < 8; ++kt) {
    uint4 Bh[8], Bl[8];
#pragma unroll
    for (int nt = 0; nt < 8; ++nt) {
      int f = ((w * 8 + nt) * 8 + kt) * 64 + l;
      Bh[nt] = bh[f];
      Bl[nt] = bl[f];
    }
    s16x8 Ah[4], Al[4];
#pragma unroll
    for (int rt = 0; rt < 4; ++rt) {
      Ah[rt] = asv(*(const uint4*)&a_hi[(rt * 16 + lm) * 264 + kt * 32 + lq * 8]);
      Al[rt] = asv(*(const uint4*)&a_lo[(rt * 16 + lm) * 264 + kt * 32 + lq * 8]);
    }
#pragma unroll
    for (int nt = 0; nt < 8; ++nt)
#pragma unroll
      for (int rt = 0; rt < 4; ++rt) {
        acc[nt][rt] = MFMA16(Ah[rt], asv(Bh[nt]), acc[nt][rt]);
        acc[nt][rt] = MFMA16(Ah[rt], asv(Bl[nt]), acc[nt][rt]);
        acc[nt][rt] = MFMA16(Al[rt], asv(Bh[nt]), acc[nt][rt]);
      }
  }
#pragma unroll
  for (int nt = 0; nt < 8; ++nt)
#pragma unroll
    for (int rt = 0; rt < 4; ++rt)
#pragma unroll
      for (int r = 0; r < 4; ++r) {
        size_t row = row0 + rt * 16 + lq * 4 + r;
        out[row * 1024 + (w * 8 + nt) * 16 + lm] = f2bu(acc[nt][rt][r]);
      }
}

// ---- phase 2: MFMA scan, M=1, fused cluster + vmcnt-preserving barrier ----
// r14 diagnosis: step ~3830cy @ ~730MHz eff.; __syncthreads drains vmcnt(0)
// every step, and the late rxf prefetch put an HBM load ~150cy before the
// barrier => ~500-750cy stall/step. Fix: (a) all fiou(t+1) prefetches in ONE
// cluster right after the barrier (rxf double-buffered), (b) raw s_barrier
// with lgkmcnt-only drain so VMEM stays in flight across steps.
#define LDH 264
#define SCAN_LDS (131072 + 2 * 16 * LDH * 2)

__global__ __launch_bounds__(512, 2) void scan3(
    const unsigned short* __restrict__ fiou, const unsigned short* __restrict__ wiouB,
    const unsigned short* __restrict__ wfB, const unsigned* __restrict__ ndg,
    float* __restrict__ X, float* __restrict__ gcs) {
  unsigned short* i_lds = (unsigned short*)smem;            // i-gate frags (128 KB)
  unsigned short* h_lds = (unsigned short*)(smem + 131072); // 16 x LDH
  unsigned short* o_lds = h_lds + 16 * LDH;                 // 16 x LDH
  __shared__ int okf;

  const int tid = threadIdx.x;
  const int w = tid >> 6, l = tid & 63;
  const int lm = l & 15, lq = l >> 4;
  const int b = blockIdx.x;          // one batch per block
  const int jj = 32 * w + lm;
  const int nt0 = 2 * w;
  const bool act = (lq == 0);        // lanes owning C row 0
  const bool arow = (lm == 0);       // lanes carrying A row 0

  if (tid == 0) okf = 1;
  const uint4* wp  = (const uint4*)wiouB;
  const uint4* wf4 = (const uint4*)wfB;
  {
    uint4* d = (uint4*)i_lds;
    for (int i = tid; i < 8192; i += 512) d[i] = wp[i];
  }
  for (int i = tid; i < 2 * 16 * LDH; i += 512) h_lds[i] = 0;
  uint4 wor[2][8], wur[2][8], wfr[2][8];
#pragma unroll
  for (int ts = 0; ts < 2; ++ts)
#pragma unroll
    for (int kt = 0; kt < 8; ++kt) {
      wor[ts][kt] = wp[((16 + (nt0 + ts)) * 8 + kt) * 64 + l];
      wur[ts][kt] = wp[((32 + (nt0 + ts)) * 8 + kt) * 64 + l];
      wfr[ts][kt] = wf4[((nt0 + ts) * 8 + kt) * 64 + l];
    }
  const unsigned* ndb = ndg + (b >> 4) * 4096 + (b & 15);  // stride 16 per t
  __syncthreads();

  if (tid < 256) {
    unsigned exp_ = (tid < 255)
        ? ((unsigned)tid | ((unsigned)(tid + 1) << 8) | 0x30000u)
        : (255u | 0x10000u);
    if (ndb[tid * 16] != exp_) atomicAnd(&okf, 0);
  }
  __syncthreads();

  const uint4* il4 = (const uint4*)i_lds;
  const f32x4 z4 = {0.f, 0.f, 0.f, 0.f};
  const size_t fb = ((size_t)b) << 18;  // fiou elems: b*256*1024
  const size_t xb = ((size_t)b) << 16;  // X/gcs elems: b*256*256

  if (okf != 0) {
    // ---------------- FAST PATH (chain, M=1, fused cluster) ----------------
    unsigned short* bufA = h_lds;  // gating(t) writes out_t here
    unsigned short* bufB = o_lds;
    float gc_[2] = {0.f, 0.f};
    // acc_iou for t=0: h_0 = 0 => exact zeros
    f32x4 accI[2] = {z4, z4}, accO[2] = {z4, z4}, accU[2] = {z4, z4};
    unsigned short rxi[2], rxo[2], rxu[2], rxf[2];
    if (act) {
#pragma unroll
      for (int ts = 0; ts < 2; ++ts) {
        int j = jj + ts * 16;
        rxi[ts] = fiou[fb + 256 + j];       // row 0 (tgt=0)
        rxo[ts] = fiou[fb + 512 + j];
        rxu[ts] = fiou[fb + 768 + j];
        rxf[ts] = fiou[fb + 1024 + j];      // row 1 (par=1), f slice
      }
    }

    for (int t = 0; t < Nn; ++t) {
      // 1) gating(t): uses acc_iou(t) (from prev cluster) + gc_{t-1}
      float mem_[2], out_[2];
      if (act) {
#pragma unroll
        for (int ts = 0; ts < 2; ++ts) {
          float I  = accI[ts][0] + bu2f(rxi[ts]);
          float O  = accO[ts][0] + bu2f(rxo[ts]);
          float Uv = accU[ts][0] + bu2f(rxu[ts]);
          float memv = sigf(I) * tanh_(Uv) + gc_[ts];
          float outv = sigf(O) * tanh_(memv);
          mem_[ts] = memv;
          out_[ts] = outv;
          bufA[jj + ts * 16] = f2bu(outv);
        }
      }
      FAST_BAR();  // out_t visible; VMEM stays in flight

      // 2) hs store + ALL fiou(t+1) prefetches in one early cluster
      const int tgtN = (t < Nn - 1) ? t + 1 : t;
      unsigned short rxf_nxt[2];
      if (act) {
#pragma unroll
        for (int ts = 0; ts < 2; ++ts)
          X[xb + (size_t)t * 256 + jj + ts * 16] = out_[ts];
        size_t fr = fb + (size_t)tgtN * 1024;
        int parN = (tgtN < 255) ? tgtN + 1 : 0;
        size_t fp = fb + (size_t)parN * 1024;
#pragma unroll
        for (int ts = 0; ts < 2; ++ts) {
          int j = jj + ts * 16;
          rxi[ts] = fiou[fr + 256 + j];
          rxo[ts] = fiou[fr + 512 + j];
          rxu[ts] = fiou[fr + 768 + j];
          rxf_nxt[ts] = fiou[fp + j];
        }
      }

      // 3) FUSED cluster: one masked read of out_t per kt feeds f(t) AND
      //    iou(t+1). 8 independent accumulator chains, 64 MFMAs.
      f32x4 aF[2] = {z4, z4};
#pragma unroll
      for (int ts = 0; ts < 2; ++ts) { accI[ts] = z4; accO[ts] = z4; accU[ts] = z4; }
#pragma unroll
      for (int kt = 0; kt < 8; ++kt) {
        uint4 av = {0u, 0u, 0u, 0u};
        if (arow) av = *(const uint4*)&bufA[kt * 32 + lq * 8];
        s16x8 a = asv(av);
#pragma unroll
        for (int ts = 0; ts < 2; ++ts) {
          aF[ts]   = MFMA16(a, asv(wfr[ts][kt]), aF[ts]);
          accI[ts] = MFMA16(a, asv(il4[((nt0 + ts) * 8 + kt) * 64 + l]), accI[ts]);
          accO[ts] = MFMA16(a, asv(wor[ts][kt]), accO[ts]);
          accU[ts] = MFMA16(a, asv(wur[ts][kt]), accU[ts]);
        }
      }

      // 4) carry: gc_t = sig(aF + xf[par_t]) * mem_t ; roll rxf buffer
      if (act) {
#pragma unroll
        for (int ts = 0; ts < 2; ++ts) {
          float AF = aF[ts][0] + bu2f(rxf[ts]);
          gc_[ts] = sigf(AF) * mem_[ts];
          rxf[ts] = rxf_nxt[ts];
        }
      }

      // ping-pong: next gating writes the other buffer (reads of bufA are
      // all pre-barrier(t+1), so bufA is reusable at t+2)
      unsigned short* tmp = bufA; bufA = bufB; bufB = tmp;
    }
  } else {
    // ---------------- SLOW PATH (general tree, M=1; as r10/r13/r14) ------
    for (int t = 0; t < Nn; ++t) {
      unsigned nd_ = ndb[t * 16];
      int tgt = nd_ & 255, par = (nd_ >> 8) & 255;

      if (tid < 256)
        h_lds[tid] = f2bu(X[xb + (size_t)tgt * 256 + tid]);

      unsigned short rxi[2], rxo[2], rxu[2], rxf[2];
      float rgc[2], xold[2], gold[2];
      if (act) {
        size_t ft = fb + (size_t)tgt * 1024;
        size_t fp = fb + (size_t)par * 1024;
#pragma unroll
        for (int ts = 0; ts < 2; ++ts) {
          int j = jj + ts * 16;
          rxi[ts] = fiou[ft + 256 + j];
          rxo[ts] = fiou[ft + 512 + j];
          rxu[ts] = fiou[ft + 768 + j];
          rxf[ts] = fiou[fp + j];
          rgc[ts]  = gcs[xb + (size_t)tgt * 256 + j];
          xold[ts] = X[xb + (size_t)par * 256 + j];
          gold[ts] = gcs[xb + (size_t)par * 256 + j];
        }
      }
      __syncthreads();

      f32x4 aI[2] = {z4, z4}, aO[2] = {z4, z4}, aU[2] = {z4, z4};
#pragma unroll
      for (int kt = 0; kt < 8; ++kt) {
        uint4 av = *(const uint4*)&h_lds[lm * LDH + kt * 32 + lq * 8];
        s16x8 a = asv(av);
#pragma unroll
        for (int ts = 0; ts < 2; ++ts) {
          aI[ts] = MFMA16(a, asv(il4[((nt0 + ts) * 8 + kt) * 64 + l]), aI[ts]);
          aO[ts] = MFMA16(a, asv(wor[ts][kt]), aO[ts]);
          aU[ts] = MFMA16(a, asv(wur[ts][kt]), aU[ts]);
        }
      }

      float mem_[2], out_[2];
      if (act) {
#pragma unroll
        for (int ts = 0; ts < 2; ++ts) {
          float I  = aI[ts][0] + bu2f(rxi[ts]);
          float O  = aO[ts][0] + bu2f(rxo[ts]);
          float Uv = aU[ts][0] + bu2f(rxu[ts]);
          float memv = sigf(I) * tanh_(Uv) + rgc[ts];
          float outv = sigf(O) * tanh_(memv);
          mem_[ts] = memv;
          out_[ts] = outv;
          o_lds[jj + ts * 16] = f2bu(outv);
        }
      }
      __syncthreads();

      f32x4 aF[2] = {z4, z4};
#pragma unroll
      for (int kt = 0; kt < 8; ++kt) {
        uint4 av = *(const uint4*)&o_lds[lm * LDH + kt * 32 + lq * 8];
        s16x8 a = asv(av);
#pragma unroll
        for (int ts = 0; ts < 2; ++ts)
          aF[ts] = MFMA16(a, asv(wfr[ts][kt]), aF[ts]);
      }

      if (act) {
#pragma unroll
        for (int ts = 0; ts < 2; ++ts) {
          int j = jj + ts * 16;
          float AF = aF[ts][0] + bu2f(rxf[ts]);
          float gated = sigf(AF) * mem_[ts];
          if (nd_ & 0x10000u) X[xb + (size_t)tgt * 256 + j] = out_[ts];
          if (nd_ & 0x20000u) {
            X[xb + (size_t)par * 256 + j] = xold[ts] + out_[ts];
            gcs[xb + (size_t)par * 256 + j] = gold[ts] + gated;
          }
        }
      }
      __syncthreads();
    }
  }
}

extern "C" void kernel_launch(void* const* d_in, const int* in_sizes, int n_in,
                              void* d_out, int out_size, void* d_ws, size_t ws_size,
                              hipStream_t stream) {
  const float* inputs = (const float*)d_in[0];
  const int* parents  = (const int*)d_in[1];
  const int* post     = (const int*)d_in[2];
  const float* xw     = (const float*)d_in[3];
  const float* hf     = (const float*)d_in[4];
  const float* hiou   = (const float*)d_in[5];
  const float* bias   = (const float*)d_in[6];
  float* X = (float*)d_out;  // csh-then-hs buffer (fast path: hs only)

  // ws layout:
  //   [0, 128 MiB)   fiou_xb bf16
  //   +134217728     gcs fp32      64 MiB
  //   +201326592     wiouB bf16    384 KiB
  //   +201719808     wfB bf16      128 KiB
  //   +201850880     ndg u32       256 KiB   (end 202113024)
  //   +202113024     xwHi bf16     512 KiB   (optional, ws permitting)
  //   +202637312     xwLo bf16     512 KiB
  char* ws = (char*)d_ws;
  bf16* fiou     = (bf16*)ws;
  float* gcs     = (float*)(ws + (size_t)134217728);
  bf16* wiouB    = (bf16*)(ws + (size_t)201326592);
  bf16* wfB      = (bf16*)(ws + (size_t)201719808);
  unsigned* ndg  = (unsigned*)(ws + (size_t)201850880);
  bf16* xwHi     = (bf16*)(ws + (size_t)202113024);
  bf16* xwLo     = (bf16*)(ws + (size_t)202637312);
  const bool big_ws = ws_size >= (size_t)202113024 + 2 * 524288;

  hipMemsetAsync(X, 0, (size_t)Bq * Nn * Uu * sizeof(float), stream);
  hipMemsetAsync(gcs, 0, (size_t)Bq * Nn * Uu * sizeof(float), stream);

  hipFuncSetAttribute(reinterpret_cast<const void*>(scan3),
                      hipFuncAttributeMaxDynamicSharedMemorySize, SCAN_LDS);

  prep_weights<<<1024, 256, 0, stream>>>(hiou, hf, wiouB, wfB);
  prep_nd<<<256, 256, 0, stream>>>(parents, post, ndg);
  if (big_ws) {
    hipFuncSetAttribute(reinterpret_cast<const void*>(xproj2),
                        hipFuncAttributeMaxDynamicSharedMemorySize, XP_LDS);
    prep_xw<<<1024, 256, 0, stream>>>(xw, xwHi, xwLo);
    xproj2<<<(Bq * Nn) / 64, 512, XP_LDS, stream>>>(
        inputs, (const unsigned short*)xwHi, (const unsigned short*)xwLo,
        bias, (unsigned short*)fiou);
  } else {
    xproj<<<(Bq * Nn) / 16, 256, 0, stream>>>(inputs, xw, bias, (bf16*)fiou);
  }
  scan3<<<256, 512, SCAN_LDS, stream>>>((const unsigned short*)fiou,
                                        (const unsigned short*)wiouB,
                                        (const unsigned short*)wfB,
                                        ndg, X, gcs);
}